// Round 2
// baseline (2809.139 us; speedup 1.0000x reference)
//
#include <hip/hip_runtime.h>
#include <math.h>

// Problem constants
#define LL   4096      // H*W
#define DI   128       // 2*C
#define CC   64        // C
#define BB   8         // batch
#define KK   4         // scan directions
#define LB   32768     // B*L pixels per instance
#define NPIX 2097152   // B*H*W*C elements of s
#define EPSF 1e-5f

// Workspace layout (floats, per instance)
#define OFF_XCIN   ((size_t)0)
#define OFF_XCONV  ((size_t)4194304)
#define OFF_XCONVT ((size_t)8388608)
#define OFF_Z      ((size_t)12582912)
#define OFF_Y      ((size_t)16777216)
#define OFF_YT     ((size_t)20971520)
#define OFF_XDBL   ((size_t)25165824)
#define ISTRIDE    ((size_t)25952256)   // floats per instance
#define OFF_SBUF   OFF_XCIN             // alias: xcin dead after conv

__device__ __forceinline__ float wave_allsum(float v){
  #pragma unroll
  for(int o=1;o<64;o<<=1) v += __shfl_xor(v,o);
  return v;
}
__device__ __forceinline__ float sigmoidf_(float x){ return 1.f/(1.f+expf(-x)); }
__device__ __forceinline__ float softplusf_(float x){ return fmaxf(x,0.f) + log1pf(expf(-fabsf(x))); }
__device__ __forceinline__ float geluf_(float x){ return 0.5f*x*(1.f+erff(x*0.70710678118f)); }

// K1: LN(norm1) + in_proj (64 -> 256), split into xc (b,d,l layout) and silu(z) (p,d layout)
__global__ __launch_bounds__(256) void k1_ln_inproj(
    const float* __restrict__ xmag, const float* __restrict__ xph,
    const float* __restrict__ n1w_, const float* __restrict__ n1b_,
    const float* __restrict__ ipw_, float* __restrict__ ws)
{
  const int i = blockIdx.y;
  const float* xin = i ? xph : xmag;
  const float* n1w = n1w_ + i*CC;
  const float* n1b = n1b_ + i*CC;
  const float* ipw = ipw_ + i*2*DI*CC;
  float* xcin = ws + (size_t)i*ISTRIDE + OFF_XCIN;
  float* zbuf = ws + (size_t)i*ISTRIDE + OFF_Z;
  __shared__ float hn[CC];
  const int t = threadIdx.x;
  for(int pp=0; pp<8; ++pp){
    const int p = blockIdx.x*8 + pp;
    const int b = p >> 12, l = p & (LL-1);
    if(t < CC){
      float v = xin[p*CC + t];
      float s1 = wave_allsum(v);
      float s2 = wave_allsum(v*v);
      float mu = s1*(1.f/CC);
      float rs = rsqrtf(s2*(1.f/CC) - mu*mu + EPSF);
      hn[t] = (v-mu)*rs*n1w[t] + n1b[t];
    }
    __syncthreads();
    float acc = 0.f;
    #pragma unroll
    for(int c=0;c<CC;++c) acc += hn[c]*ipw[t*CC + c];
    if(t < DI){
      xcin[((size_t)(b*DI + t))*LL + l] = acc;
    } else {
      zbuf[(size_t)p*DI + (t-DI)] = acc * sigmoidf_(acc);   // silu
    }
    __syncthreads();
  }
}

// K2: depthwise 3x3 conv + silu; per (b,d) 64x64 tile via LDS; writes row-major and transposed
__global__ __launch_bounds__(256) void k2_dwconv(
    const float* __restrict__ cw_, float* __restrict__ ws)
{
  const int i = blockIdx.y;
  const int bd = blockIdx.x;            // b*DI + d
  const int d = bd & (DI-1);
  const float* cw = cw_ + i*DI*9 + d*9;
  const float* xcin  = ws + (size_t)i*ISTRIDE + OFF_XCIN  + (size_t)bd*LL;
  float* xconv  = ws + (size_t)i*ISTRIDE + OFF_XCONV  + (size_t)bd*LL;
  float* xconvT = ws + (size_t)i*ISTRIDE + OFF_XCONVT + (size_t)bd*LL;
  __shared__ float tin[64*65];
  __shared__ float tout[64*65];
  const int t = threadIdx.x;
  float w9[9];
  #pragma unroll
  for(int q=0;q<9;++q) w9[q] = cw[q];
  for(int idx=t; idx<4096; idx+=256)
    tin[(idx>>6)*65 + (idx&63)] = xcin[idx];
  __syncthreads();
  const int w = t & 63, hb = (t>>6)*16;
  #pragma unroll
  for(int r=0;r<16;++r){
    const int h = hb + r;
    float acc = 0.f;
    #pragma unroll
    for(int dy=0;dy<3;++dy){
      const int hh = h + dy - 1;
      if(hh>=0 && hh<64){
        #pragma unroll
        for(int dx=0;dx<3;++dx){
          const int ww = w + dx - 1;
          if(ww>=0 && ww<64) acc += tin[hh*65+ww]*w9[dy*3+dx];
        }
      }
    }
    const float o = acc * sigmoidf_(acc);  // silu
    tout[h*65+w] = o;
    xconv[h*64+w] = o;
  }
  __syncthreads();
  const int hcol = t & 63, wb = (t>>6)*16;
  #pragma unroll
  for(int r=0;r<16;++r){
    const int wp = wb + r;
    xconvT[wp*64 + hcol] = tout[hcol*65 + wp];   // stride-65 LDS read: conflict-free
  }
}

// K3a: x_dbl = x_proj(xs) -> (dts[4], Bs, Cs) per (b,k,scan-pos)
__global__ __launch_bounds__(256) void k3a_xproj(
    const float* __restrict__ xpw_, float* __restrict__ ws)
{
  const int i = blockIdx.z;
  const int b = blockIdx.y >> 2;
  const int k = blockIdx.y & 3;
  const int l = blockIdx.x*256 + threadIdx.x;
  const float* src = ws + (size_t)i*ISTRIDE + ((k&1)? OFF_XCONVT : OFF_XCONV) + (size_t)b*DI*LL;
  const int ridx = (k>=2) ? (LL-1-l) : l;
  const float* xpw = xpw_ + i*KK*6*DI + k*6*DI;
  float acc[6] = {0,0,0,0,0,0};
  for(int d=0; d<DI; ++d){
    const float xv = src[(size_t)d*LL + ridx];
    #pragma unroll
    for(int c=0;c<6;++c) acc[c] += xv * xpw[c*DI + d];
  }
  float* xdbl = ws + (size_t)i*ISTRIDE + OFF_XDBL + (size_t)(b*KK+k)*6*LL;
  #pragma unroll
  for(int c=0;c<6;++c) xdbl[(size_t)c*LL + l] = acc[c];
}

// K3b: selective scan per (b,k,d); block-parallel associative scan over L=4096
__global__ __launch_bounds__(256) void k3b_scan(
    const float* __restrict__ dtw_, const float* __restrict__ dtb_,
    const float* __restrict__ alog_, const float* __restrict__ Ds_,
    float* __restrict__ ws)
{
  const int gid = blockIdx.x;           // b*512 + k*128 + d
  const int i = blockIdx.y;
  const int d = gid & (DI-1);
  const int k = (gid >> 7) & 3;
  const int b = gid >> 9;
  const int t = threadIdx.x;
  float* base = ws + (size_t)i*ISTRIDE;
  const float* src = base + ((k&1)? OFF_XCONVT : OFF_XCONV) + (size_t)(b*DI+d)*LL;
  float*       dst = base + ((k&1)? OFF_YT    : OFF_Y    ) + (size_t)(b*DI+d)*LL;
  const float* xd  = base + OFF_XDBL + (size_t)(b*KK+k)*6*LL;
  const int kd = k*DI + d;
  const float dtw0 = dtw_[i*KK*DI*4 + kd*4 + 0];
  const float dtw1 = dtw_[i*KK*DI*4 + kd*4 + 1];
  const float dtw2 = dtw_[i*KK*DI*4 + kd*4 + 2];
  const float dtw3 = dtw_[i*KK*DI*4 + kd*4 + 3];
  const float dbias= dtb_[i*KK*DI + kd];
  const float Av   = -expf(alog_[i*KK*DI + kd]);
  const float Dv   = Ds_[i*KK*DI + kd];
  const bool rev = (k>=2);
  float aA[16], bA[16], cA[16], dA[16];
  float accA = 1.f, accB = 0.f;
  const int l0 = t*16;
  #pragma unroll
  for(int j=0;j<16;++j){
    const int l = l0 + j;
    const int r = rev ? (LL-1-l) : l;
    const float pre = dbias + dtw0*xd[l] + dtw1*xd[LL+l] + dtw2*xd[2*LL+l] + dtw3*xd[3*LL+l];
    const float delta = softplusf_(pre);
    const float bs = xd[4*LL + l];
    const float cs = xd[5*LL + l];
    const float xv = src[r];
    const float a  = expf(delta * Av);
    const float bb = delta * bs * xv;
    aA[j]=a; bA[j]=bb; cA[j]=cs; dA[j]=Dv*xv;
    accB = accB*a + bb;
    accA *= a;
  }
  __shared__ float sA[256], sB[256];
  sA[t]=accA; sB[t]=accB;
  __syncthreads();
  #pragma unroll
  for(int off=1; off<256; off<<=1){
    float aL=1.f, bL=0.f;
    if(t>=off){ aL=sA[t-off]; bL=sB[t-off]; }
    __syncthreads();
    if(t>=off){ accB = bL*accA + accB; accA = aL*accA; sA[t]=accA; sB[t]=accB; }
    __syncthreads();
  }
  float h = (t>0) ? sB[t-1] : 0.f;
  #pragma unroll
  for(int j=0;j<16;++j){
    h = aA[j]*h + bA[j];
    const int l = l0 + j;
    const int r = rev ? (LL-1-l) : l;
    atomicAdd(&dst[r], h*cA[j] + dA[j]);
  }
}

// K4: epilogue per pixel: out_norm LN, *z, out_proj, residual, norm2 LN, MLP+GELU, residual
__global__ __launch_bounds__(128) void k4_epilogue(
    const float* __restrict__ xmag, const float* __restrict__ xph,
    const float* __restrict__ onw_, const float* __restrict__ onb_,
    const float* __restrict__ opw_,
    const float* __restrict__ n2w_, const float* __restrict__ n2b_,
    const float* __restrict__ f1w_, const float* __restrict__ f1b_,
    const float* __restrict__ f2w_, const float* __restrict__ f2b_,
    float* __restrict__ ws)
{
  const int i = blockIdx.y;
  const float* xin = i ? xph : xmag;
  const float* onw = onw_ + i*DI;
  const float* onb = onb_ + i*DI;
  const float* opw = opw_ + i*CC*DI;
  const float* n2w = n2w_ + i*CC;
  const float* n2b = n2b_ + i*CC;
  const float* f1w = f1w_ + i*4*CC*CC;
  const float* f1b = f1b_ + i*4*CC;
  const float* f2w = f2w_ + i*4*CC*CC;
  const float* f2b = f2b_ + i*CC;
  float* base = ws + (size_t)i*ISTRIDE;
  const float* y  = base + OFF_Y;
  const float* yT = base + OFF_YT;
  const float* z  = base + OFF_Z;
  float* sbuf = base + OFF_SBUF;
  __shared__ float yn_[DI];
  __shared__ float h2_[CC];
  __shared__ float gl_[4*CC];
  __shared__ float red[4];
  const int t = threadIdx.x;
  for(int pp=0; pp<8; ++pp){
    const int p = blockIdx.x*8 + pp;
    const int b = p >> 12, l = p & (LL-1);
    const int hR = l >> 6, wR = l & 63;
    const size_t rowbase = (size_t)(b*DI + t)*LL;
    const float yv = y[rowbase + l] + yT[rowbase + (wR*64 + hR)];
    const float s1 = wave_allsum(yv), s2 = wave_allsum(yv*yv);
    if((t&63)==0){ red[(t>>6)*2]=s1; red[(t>>6)*2+1]=s2; }
    __syncthreads();
    const float S1 = red[0]+red[2], S2 = red[1]+red[3];
    const float mu = S1*(1.f/DI);
    const float rs = rsqrtf(S2*(1.f/DI) - mu*mu + EPSF);
    yn_[t] = ((yv-mu)*rs*onw[t] + onb[t]) * z[(size_t)p*DI + t];
    __syncthreads();
    float xnew = 0.f;
    if(t < CC){
      float acc = 0.f;
      #pragma unroll
      for(int dd=0; dd<DI; ++dd) acc += yn_[dd]*opw[t*DI+dd];
      xnew = xin[p*CC + t] + acc;
      const float m1 = wave_allsum(xnew), m2 = wave_allsum(xnew*xnew);
      const float mu2 = m1*(1.f/CC);
      const float rs2 = rsqrtf(m2*(1.f/CC) - mu2*mu2 + EPSF);
      h2_[t] = (xnew-mu2)*rs2*n2w[t] + n2b[t];
    }
    __syncthreads();
    #pragma unroll
    for(int jj=0; jj<2; ++jj){
      const int j = t + jj*128;
      float acc = f1b[j];
      #pragma unroll
      for(int c=0;c<CC;++c) acc += h2_[c]*f1w[j*CC+c];
      gl_[j] = geluf_(acc);
    }
    __syncthreads();
    if(t < CC){
      float acc = f2b[t];
      #pragma unroll
      for(int j=0;j<4*CC;++j) acc += gl_[j]*f2w[t*4*CC + j];
      sbuf[(size_t)p*CC + t] = xnew + acc;
    }
    __syncthreads();
  }
}

// K5: s = inst0 + inst1; write to both output halves
__global__ __launch_bounds__(256) void k5_final(
    const float* __restrict__ ws, float* __restrict__ out)
{
  const int idx = blockIdx.x*256 + threadIdx.x;
  const float v = ws[OFF_SBUF + idx] + ws[ISTRIDE + OFF_SBUF + idx];
  out[idx] = v;
  out[NPIX + idx] = v;
}

extern "C" void kernel_launch(void* const* d_in, const int* in_sizes, int n_in,
                              void* d_out, int out_size, void* d_ws, size_t ws_size,
                              hipStream_t stream)
{
  const float* mag  = (const float*)d_in[0];
  const float* ph   = (const float*)d_in[1];
  const float* n1w  = (const float*)d_in[2];
  const float* n1b  = (const float*)d_in[3];
  const float* ipw  = (const float*)d_in[4];
  const float* cw   = (const float*)d_in[5];
  const float* xpw  = (const float*)d_in[6];
  const float* dtw  = (const float*)d_in[7];
  const float* dtb  = (const float*)d_in[8];
  const float* alog = (const float*)d_in[9];
  const float* Ds   = (const float*)d_in[10];
  const float* onw  = (const float*)d_in[11];
  const float* onb  = (const float*)d_in[12];
  const float* opw  = (const float*)d_in[13];
  const float* n2w  = (const float*)d_in[14];
  const float* n2b  = (const float*)d_in[15];
  const float* f1w  = (const float*)d_in[16];
  const float* f1b  = (const float*)d_in[17];
  const float* f2w  = (const float*)d_in[18];
  const float* f2b  = (const float*)d_in[19];
  float* ws = (float*)d_ws;
  float* out = (float*)d_out;

  // zero the atomic-accumulated y / yT buffers (adjacent per instance)
  for(int i=0;i<2;++i)
    hipMemsetAsync(ws + (size_t)i*ISTRIDE + OFF_Y, 0, (size_t)2*4194304*sizeof(float), stream);

  k1_ln_inproj<<<dim3(4096,2), 256, 0, stream>>>(mag, ph, n1w, n1b, ipw, ws);
  k2_dwconv  <<<dim3(1024,2), 256, 0, stream>>>(cw, ws);
  k3a_xproj  <<<dim3(16,32,2),256, 0, stream>>>(xpw, ws);
  k3b_scan   <<<dim3(4096,2), 256, 0, stream>>>(dtw, dtb, alog, Ds, ws);
  k4_epilogue<<<dim3(4096,2), 128, 0, stream>>>(mag, ph, onw, onb, opw, n2w, n2b,
                                                f1w, f1b, f2w, f2b, ws);
  k5_final   <<<dim3(8192),   256, 0, stream>>>(ws, out);
}

// Round 3
// 1335.522 us; speedup vs baseline: 2.1034x; 2.1034x over previous
//
#include <hip/hip_runtime.h>
#include <math.h>

// Problem constants
#define LL   4096      // H*W
#define DI   128       // 2*C
#define CC   64        // C
#define BB   8         // batch
#define KK   4         // scan directions
#define NPIX 2097152   // B*H*W*C elements of s
#define EPSF 1e-5f

// Workspace layout (floats, per instance)
#define OFF_XCIN   ((size_t)0)
#define OFF_XCONV  ((size_t)4194304)
#define OFF_XCONVT ((size_t)8388608)
#define OFF_Z      ((size_t)12582912)
#define OFF_Y      ((size_t)16777216)
#define OFF_YT     ((size_t)20971520)
#define OFF_XDBL   ((size_t)25165824)
#define ISTRIDE    ((size_t)25952256)   // floats per instance
#define OFF_SBUF   OFF_XCIN             // alias: xcin dead after conv

__device__ __forceinline__ float wave_allsum(float v){
  #pragma unroll
  for(int o=1;o<64;o<<=1) v += __shfl_xor(v,o);
  return v;
}
__device__ __forceinline__ float sigmoidf_(float x){ return 1.f/(1.f+expf(-x)); }
__device__ __forceinline__ float softplusf_(float x){ return fmaxf(x,0.f) + log1pf(expf(-fabsf(x))); }
__device__ __forceinline__ float geluf_(float x){ return 0.5f*x*(1.f+erff(x*0.70710678118f)); }

// load 16 consecutive floats (16B-aligned) into dst[0..15]
#define LD16(dst, ptr) { const float4* p4_=(const float4*)(ptr);                 \
  float4 v0_=p4_[0], v1_=p4_[1], v2_=p4_[2], v3_=p4_[3];                         \
  dst[0]=v0_.x; dst[1]=v0_.y; dst[2]=v0_.z; dst[3]=v0_.w;                        \
  dst[4]=v1_.x; dst[5]=v1_.y; dst[6]=v1_.z; dst[7]=v1_.w;                        \
  dst[8]=v2_.x; dst[9]=v2_.y; dst[10]=v2_.z; dst[11]=v2_.w;                      \
  dst[12]=v3_.x; dst[13]=v3_.y; dst[14]=v3_.z; dst[15]=v3_.w; }
// load 16 consecutive floats and store REVERSED: dst[15-m] = ptr[m]
#define LD16R(dst, ptr) { const float4* p4_=(const float4*)(ptr);                \
  float4 v0_=p4_[0], v1_=p4_[1], v2_=p4_[2], v3_=p4_[3];                         \
  dst[15]=v0_.x; dst[14]=v0_.y; dst[13]=v0_.z; dst[12]=v0_.w;                    \
  dst[11]=v1_.x; dst[10]=v1_.y; dst[9]=v1_.z;  dst[8]=v1_.w;                     \
  dst[7]=v2_.x;  dst[6]=v2_.y;  dst[5]=v2_.z;  dst[4]=v2_.w;                     \
  dst[3]=v3_.x;  dst[2]=v3_.y;  dst[1]=v3_.z;  dst[0]=v3_.w; }

// K1: LN(norm1) + in_proj (64 -> 256), split into xc (b,d,l layout) and silu(z) (p,d layout)
__global__ __launch_bounds__(256) void k1_ln_inproj(
    const float* __restrict__ xmag, const float* __restrict__ xph,
    const float* __restrict__ n1w_, const float* __restrict__ n1b_,
    const float* __restrict__ ipw_, float* __restrict__ ws)
{
  const int i = blockIdx.y;
  const float* xin = i ? xph : xmag;
  const float* n1w = n1w_ + i*CC;
  const float* n1b = n1b_ + i*CC;
  const float* ipw = ipw_ + i*2*DI*CC;
  float* xcin = ws + (size_t)i*ISTRIDE + OFF_XCIN;
  float* zbuf = ws + (size_t)i*ISTRIDE + OFF_Z;
  __shared__ float hn[CC];
  const int t = threadIdx.x;
  for(int pp=0; pp<8; ++pp){
    const int p = blockIdx.x*8 + pp;
    const int b = p >> 12, l = p & (LL-1);
    if(t < CC){
      float v = xin[p*CC + t];
      float s1 = wave_allsum(v);
      float s2 = wave_allsum(v*v);
      float mu = s1*(1.f/CC);
      float rs = rsqrtf(s2*(1.f/CC) - mu*mu + EPSF);
      hn[t] = (v-mu)*rs*n1w[t] + n1b[t];
    }
    __syncthreads();
    float acc = 0.f;
    #pragma unroll
    for(int c=0;c<CC;++c) acc += hn[c]*ipw[t*CC + c];
    if(t < DI){
      xcin[((size_t)(b*DI + t))*LL + l] = acc;
    } else {
      zbuf[(size_t)p*DI + (t-DI)] = acc * sigmoidf_(acc);   // silu
    }
    __syncthreads();
  }
}

// K2: depthwise 3x3 conv + silu; per (b,d) 64x64 tile via LDS; writes row-major and transposed
__global__ __launch_bounds__(256) void k2_dwconv(
    const float* __restrict__ cw_, float* __restrict__ ws)
{
  const int i = blockIdx.y;
  const int bd = blockIdx.x;            // b*DI + d
  const int d = bd & (DI-1);
  const float* cw = cw_ + i*DI*9 + d*9;
  const float* xcin  = ws + (size_t)i*ISTRIDE + OFF_XCIN  + (size_t)bd*LL;
  float* xconv  = ws + (size_t)i*ISTRIDE + OFF_XCONV  + (size_t)bd*LL;
  float* xconvT = ws + (size_t)i*ISTRIDE + OFF_XCONVT + (size_t)bd*LL;
  __shared__ float tin[64*65];
  __shared__ float tout[64*65];
  const int t = threadIdx.x;
  float w9[9];
  #pragma unroll
  for(int q=0;q<9;++q) w9[q] = cw[q];
  for(int idx=t; idx<4096; idx+=256)
    tin[(idx>>6)*65 + (idx&63)] = xcin[idx];
  __syncthreads();
  const int w = t & 63, hb = (t>>6)*16;
  #pragma unroll
  for(int r=0;r<16;++r){
    const int h = hb + r;
    float acc = 0.f;
    #pragma unroll
    for(int dy=0;dy<3;++dy){
      const int hh = h + dy - 1;
      if(hh>=0 && hh<64){
        #pragma unroll
        for(int dx=0;dx<3;++dx){
          const int ww = w + dx - 1;
          if(ww>=0 && ww<64) acc += tin[hh*65+ww]*w9[dy*3+dx];
        }
      }
    }
    const float o = acc * sigmoidf_(acc);  // silu
    tout[h*65+w] = o;
    xconv[h*64+w] = o;
  }
  __syncthreads();
  const int hcol = t & 63, wb = (t>>6)*16;
  #pragma unroll
  for(int r=0;r<16;++r){
    const int wp = wb + r;
    xconvT[wp*64 + hcol] = tout[hcol*65 + wp];   // stride-65 LDS read: conflict-free
  }
}

// K3a: x_dbl = x_proj(xs) -> (dts[4], Bs, Cs) per (b,k,scan-pos)
__global__ __launch_bounds__(256) void k3a_xproj(
    const float* __restrict__ xpw_, float* __restrict__ ws)
{
  const int i = blockIdx.z;
  const int b = blockIdx.y >> 2;
  const int k = blockIdx.y & 3;
  const int l = blockIdx.x*256 + threadIdx.x;
  const float* src = ws + (size_t)i*ISTRIDE + ((k&1)? OFF_XCONVT : OFF_XCONV) + (size_t)b*DI*LL;
  const int ridx = (k>=2) ? (LL-1-l) : l;
  const float* xpw = xpw_ + i*KK*6*DI + k*6*DI;
  float acc[6] = {0,0,0,0,0,0};
  for(int d=0; d<DI; ++d){
    const float xv = src[(size_t)d*LL + ridx];
    #pragma unroll
    for(int c=0;c<6;++c) acc[c] += xv * xpw[c*DI + d];
  }
  float* xdbl = ws + (size_t)i*ISTRIDE + OFF_XDBL + (size_t)(b*KK+k)*6*LL;
  #pragma unroll
  for(int c=0;c<6;++c) xdbl[(size_t)c*LL + l] = acc[c];
}

// K3b v2: paired fwd/bwd selective scan per (b, kpair, d). No atomics: the pair
// (k, k+2) shares one source row and one destination row; forward scan (k) and
// suffix scan (k+2) are combined and written once with full-line float4 stores.
__global__ __launch_bounds__(256) void k3b_scan(
    const float* __restrict__ dtw_, const float* __restrict__ dtb_,
    const float* __restrict__ alog_, const float* __restrict__ Ds_,
    float* __restrict__ ws)
{
  const int gid = blockIdx.x;           // b*256 + kp*128 + d
  const int i = blockIdx.y;
  const int d  = gid & (DI-1);
  const int kp = (gid >> 7) & 1;        // 0: rows (k=0,2)  1: cols (k=1,3)
  const int b  = gid >> 8;
  const int t = threadIdx.x;
  float* base = ws + (size_t)i*ISTRIDE;
  const float* src = base + (kp? OFF_XCONVT : OFF_XCONV) + (size_t)(b*DI+d)*LL;
  float*       dst = base + (kp? OFF_YT    : OFF_Y    ) + (size_t)(b*DI+d)*LL;
  const float* xdF = base + OFF_XDBL + (size_t)(b*KK+kp  )*6*LL;   // k = kp
  const float* xdB = base + OFF_XDBL + (size_t)(b*KK+kp+2)*6*LL;   // k = kp+2
  const int kdF = kp*DI + d, kdB = (kp+2)*DI + d;
  const float4 wF = ((const float4*)dtw_)[i*KK*DI + kdF];
  const float4 wB = ((const float4*)dtw_)[i*KK*DI + kdB];
  const float biasF = dtb_[i*KK*DI + kdF], biasB = dtb_[i*KK*DI + kdB];
  const float AvF = -expf(alog_[i*KK*DI + kdF]);
  const float AvB = -expf(alog_[i*KK*DI + kdB]);
  const float Dsum = Ds_[i*KK*DI + kdF] + Ds_[i*KK*DI + kdB];
  const int l0 = t*16;          // this thread's contiguous chunk [l0, l0+16)
  const int s0 = LL - 16 - l0;  // backward direction's scan positions for chunk

  float vX[16], aF[16], bF[16], cF[16], aB[16], bB[16], cB[16];
  float pre[16], r0[16];
  LD16(vX, src + l0);

  // ---- forward (k = kp): scan position == l ----
  LD16(r0, xdF + 0*LL + l0);
  #pragma unroll
  for(int j=0;j<16;++j) pre[j] = biasF + wF.x*r0[j];
  LD16(r0, xdF + 1*LL + l0);
  #pragma unroll
  for(int j=0;j<16;++j) pre[j] += wF.y*r0[j];
  LD16(r0, xdF + 2*LL + l0);
  #pragma unroll
  for(int j=0;j<16;++j) pre[j] += wF.z*r0[j];
  LD16(r0, xdF + 3*LL + l0);
  #pragma unroll
  for(int j=0;j<16;++j) pre[j] += wF.w*r0[j];
  LD16(r0, xdF + 4*LL + l0);   // Bs
  float fA = 1.f, fB = 0.f;
  #pragma unroll
  for(int j=0;j<16;++j){
    const float delta = softplusf_(pre[j]);
    aF[j] = expf(delta*AvF);
    bF[j] = delta*r0[j]*vX[j];
    fB = fB*aF[j] + bF[j];
    fA *= aF[j];
  }
  LD16(cF, xdF + 5*LL + l0);   // Cs

  // ---- backward (k = kp+2): scan position s = LL-1-l, stored reversed ----
  LD16R(r0, xdB + 0*LL + s0);
  #pragma unroll
  for(int j=0;j<16;++j) pre[j] = biasB + wB.x*r0[j];
  LD16R(r0, xdB + 1*LL + s0);
  #pragma unroll
  for(int j=0;j<16;++j) pre[j] += wB.y*r0[j];
  LD16R(r0, xdB + 2*LL + s0);
  #pragma unroll
  for(int j=0;j<16;++j) pre[j] += wB.z*r0[j];
  LD16R(r0, xdB + 3*LL + s0);
  #pragma unroll
  for(int j=0;j<16;++j) pre[j] += wB.w*r0[j];
  LD16R(r0, xdB + 4*LL + s0);  // Bs (reversed into l-order)
  float gA = 1.f, gB = 0.f;
  #pragma unroll
  for(int j=15;j>=0;--j){
    const float delta = softplusf_(pre[j]);
    aB[j] = expf(delta*AvB);
    bB[j] = delta*r0[j]*vX[j];
    gB = gB*aB[j] + bB[j];
    gA *= aB[j];
  }
  LD16R(cB, xdB + 5*LL + s0);  // Cs (reversed into l-order)

  // ---- block-level scans: prefix (fwd) and suffix (bwd) over thread aggregates ----
  __shared__ float sAf[256], sBf[256], sAb[256], sBb[256];
  sAf[t]=fA; sBf[t]=fB; sAb[t]=gA; sBb[t]=gB;
  __syncthreads();
  #pragma unroll
  for(int off=1; off<256; off<<=1){
    float aL=1.f, bL=0.f, aR=1.f, bR=0.f;
    if(t>=off){ aL=sAf[t-off]; bL=sBf[t-off]; }
    if(t+off<256){ aR=sAb[t+off]; bR=sBb[t+off]; }
    __syncthreads();
    if(t>=off){ fB = bL*fA + fB; fA = aL*fA; sAf[t]=fA; sBf[t]=fB; }
    if(t+off<256){ gB = gA*bR + gB; gA = gA*aR; sAb[t]=gA; sBb[t]=gB; }
    __syncthreads();
  }
  float hf = (t>0)   ? sBf[t-1] : 0.f;   // state entering chunk from the left
  float hb = (t<255) ? sBb[t+1] : 0.f;   // state entering chunk from the right
  #pragma unroll
  for(int j=0;j<16;++j){
    hf = aF[j]*hf + bF[j];
    vX[j] = hf*cF[j] + Dsum*vX[j];       // fwd contribution + D terms
  }
  #pragma unroll
  for(int j=15;j>=0;--j){
    hb = aB[j]*hb + bB[j];
    vX[j] += hb*cB[j];                   // bwd contribution
  }
  float4* d4 = (float4*)(dst + l0);
  d4[0] = make_float4(vX[0],vX[1],vX[2],vX[3]);
  d4[1] = make_float4(vX[4],vX[5],vX[6],vX[7]);
  d4[2] = make_float4(vX[8],vX[9],vX[10],vX[11]);
  d4[3] = make_float4(vX[12],vX[13],vX[14],vX[15]);
}

// K4: epilogue per pixel: out_norm LN, *z, out_proj, residual, norm2 LN, MLP+GELU, residual
__global__ __launch_bounds__(128) void k4_epilogue(
    const float* __restrict__ xmag, const float* __restrict__ xph,
    const float* __restrict__ onw_, const float* __restrict__ onb_,
    const float* __restrict__ opw_,
    const float* __restrict__ n2w_, const float* __restrict__ n2b_,
    const float* __restrict__ f1w_, const float* __restrict__ f1b_,
    const float* __restrict__ f2w_, const float* __restrict__ f2b_,
    float* __restrict__ ws)
{
  const int i = blockIdx.y;
  const float* xin = i ? xph : xmag;
  const float* onw = onw_ + i*DI;
  const float* onb = onb_ + i*DI;
  const float* opw = opw_ + i*CC*DI;
  const float* n2w = n2w_ + i*CC;
  const float* n2b = n2b_ + i*CC;
  const float* f1w = f1w_ + i*4*CC*CC;
  const float* f1b = f1b_ + i*4*CC;
  const float* f2w = f2w_ + i*4*CC*CC;
  const float* f2b = f2b_ + i*CC;
  float* base = ws + (size_t)i*ISTRIDE;
  const float* y  = base + OFF_Y;
  const float* yT = base + OFF_YT;
  const float* z  = base + OFF_Z;
  float* sbuf = base + OFF_SBUF;
  __shared__ float yn_[DI];
  __shared__ float h2_[CC];
  __shared__ float gl_[4*CC];
  __shared__ float red[4];
  const int t = threadIdx.x;
  for(int pp=0; pp<8; ++pp){
    const int p = blockIdx.x*8 + pp;
    const int b = p >> 12, l = p & (LL-1);
    const int hR = l >> 6, wR = l & 63;
    const size_t rowbase = (size_t)(b*DI + t)*LL;
    const float yv = y[rowbase + l] + yT[rowbase + (wR*64 + hR)];
    const float s1 = wave_allsum(yv), s2 = wave_allsum(yv*yv);
    if((t&63)==0){ red[(t>>6)*2]=s1; red[(t>>6)*2+1]=s2; }
    __syncthreads();
    const float S1 = red[0]+red[2], S2 = red[1]+red[3];
    const float mu = S1*(1.f/DI);
    const float rs = rsqrtf(S2*(1.f/DI) - mu*mu + EPSF);
    yn_[t] = ((yv-mu)*rs*onw[t] + onb[t]) * z[(size_t)p*DI + t];
    __syncthreads();
    float xnew = 0.f;
    if(t < CC){
      float acc = 0.f;
      #pragma unroll
      for(int dd=0; dd<DI; ++dd) acc += yn_[dd]*opw[t*DI+dd];
      xnew = xin[p*CC + t] + acc;
      const float m1 = wave_allsum(xnew), m2 = wave_allsum(xnew*xnew);
      const float mu2 = m1*(1.f/CC);
      const float rs2 = rsqrtf(m2*(1.f/CC) - mu2*mu2 + EPSF);
      h2_[t] = (xnew-mu2)*rs2*n2w[t] + n2b[t];
    }
    __syncthreads();
    #pragma unroll
    for(int jj=0; jj<2; ++jj){
      const int j = t + jj*128;
      float acc = f1b[j];
      #pragma unroll
      for(int c=0;c<CC;++c) acc += h2_[c]*f1w[j*CC+c];
      gl_[j] = geluf_(acc);
    }
    __syncthreads();
    if(t < CC){
      float acc = f2b[t];
      #pragma unroll
      for(int j=0;j<4*CC;++j) acc += gl_[j]*f2w[t*4*CC + j];
      sbuf[(size_t)p*CC + t] = xnew + acc;
    }
    __syncthreads();
  }
}

// K5: s = inst0 + inst1; write to both output halves
__global__ __launch_bounds__(256) void k5_final(
    const float* __restrict__ ws, float* __restrict__ out)
{
  const int idx = blockIdx.x*256 + threadIdx.x;
  const float v = ws[OFF_SBUF + idx] + ws[ISTRIDE + OFF_SBUF + idx];
  out[idx] = v;
  out[NPIX + idx] = v;
}

extern "C" void kernel_launch(void* const* d_in, const int* in_sizes, int n_in,
                              void* d_out, int out_size, void* d_ws, size_t ws_size,
                              hipStream_t stream)
{
  const float* mag  = (const float*)d_in[0];
  const float* ph   = (const float*)d_in[1];
  const float* n1w  = (const float*)d_in[2];
  const float* n1b  = (const float*)d_in[3];
  const float* ipw  = (const float*)d_in[4];
  const float* cw   = (const float*)d_in[5];
  const float* xpw  = (const float*)d_in[6];
  const float* dtw  = (const float*)d_in[7];
  const float* dtb  = (const float*)d_in[8];
  const float* alog = (const float*)d_in[9];
  const float* Ds   = (const float*)d_in[10];
  const float* onw  = (const float*)d_in[11];
  const float* onb  = (const float*)d_in[12];
  const float* opw  = (const float*)d_in[13];
  const float* n2w  = (const float*)d_in[14];
  const float* n2b  = (const float*)d_in[15];
  const float* f1w  = (const float*)d_in[16];
  const float* f1b  = (const float*)d_in[17];
  const float* f2w  = (const float*)d_in[18];
  const float* f2b  = (const float*)d_in[19];
  float* ws = (float*)d_ws;
  float* out = (float*)d_out;

  k1_ln_inproj<<<dim3(4096,2), 256, 0, stream>>>(mag, ph, n1w, n1b, ipw, ws);
  k2_dwconv  <<<dim3(1024,2), 256, 0, stream>>>(cw, ws);
  k3a_xproj  <<<dim3(16,32,2),256, 0, stream>>>(xpw, ws);
  k3b_scan   <<<dim3(2048,2), 256, 0, stream>>>(dtw, dtb, alog, Ds, ws);
  k4_epilogue<<<dim3(4096,2), 128, 0, stream>>>(mag, ph, onw, onb, opw, n2w, n2b,
                                                f1w, f1b, f2w, f2b, ws);
  k5_final   <<<dim3(8192),   256, 0, stream>>>(ws, out);
}

// Round 4
// 1008.859 us; speedup vs baseline: 2.7845x; 1.3238x over previous
//
#include <hip/hip_runtime.h>
#include <math.h>

// Problem constants
#define LL   4096      // H*W
#define DI   128       // 2*C
#define CC   64        // C
#define BB   8         // batch
#define KK   4         // scan directions
#define NPIX 2097152   // B*H*W*C elements of s
#define EPSF 1e-5f

// Workspace layout (floats, per instance)
#define OFF_XCIN   ((size_t)0)
#define OFF_XCONV  ((size_t)4194304)
#define OFF_XCONVT ((size_t)8388608)
#define OFF_Z      ((size_t)12582912)
#define OFF_Y      ((size_t)16777216)
#define OFF_YT     ((size_t)20971520)
#define OFF_XDBL   ((size_t)25165824)
#define ISTRIDE    ((size_t)25952256)   // floats per instance
// Aliases (lifetime-disjoint reuse):
#define OFF_YCOMB  OFF_XCIN             // xcin dead after k2; ycomb written by k3c
#define OFF_XNEW   OFF_YT               // yT dead after k3c; xnew written by k4a
#define OFF_SB     OFF_Y                // y dead after k3c; sbuf written by k4b (2097152 floats)
#define OFF_F2WT   (OFF_Y + (size_t)2097152)  // upper half of Y region: f2w transposed (16384 floats)

__device__ __forceinline__ float wave_allsum(float v){
  #pragma unroll
  for(int o=1;o<64;o<<=1) v += __shfl_xor(v,o);
  return v;
}
__device__ __forceinline__ float sigmoidf_(float x){ return 1.f/(1.f+expf(-x)); }
__device__ __forceinline__ float softplusf_(float x){ return fmaxf(x,0.f) + log1pf(expf(-fabsf(x))); }
__device__ __forceinline__ float geluf_(float x){ return 0.5f*x*(1.f+erff(x*0.70710678118f)); }

// load 16 consecutive floats (16B-aligned) into dst[0..15]
#define LD16(dst, ptr) { const float4* p4_=(const float4*)(ptr);                 \
  float4 v0_=p4_[0], v1_=p4_[1], v2_=p4_[2], v3_=p4_[3];                         \
  dst[0]=v0_.x; dst[1]=v0_.y; dst[2]=v0_.z; dst[3]=v0_.w;                        \
  dst[4]=v1_.x; dst[5]=v1_.y; dst[6]=v1_.z; dst[7]=v1_.w;                        \
  dst[8]=v2_.x; dst[9]=v2_.y; dst[10]=v2_.z; dst[11]=v2_.w;                      \
  dst[12]=v3_.x; dst[13]=v3_.y; dst[14]=v3_.z; dst[15]=v3_.w; }
// load 16 consecutive floats and store REVERSED: dst[15-m] = ptr[m]
#define LD16R(dst, ptr) { const float4* p4_=(const float4*)(ptr);                \
  float4 v0_=p4_[0], v1_=p4_[1], v2_=p4_[2], v3_=p4_[3];                         \
  dst[15]=v0_.x; dst[14]=v0_.y; dst[13]=v0_.z; dst[12]=v0_.w;                    \
  dst[11]=v1_.x; dst[10]=v1_.y; dst[9]=v1_.z;  dst[8]=v1_.w;                     \
  dst[7]=v2_.x;  dst[6]=v2_.y;  dst[5]=v2_.z;  dst[4]=v2_.w;                     \
  dst[3]=v3_.x;  dst[2]=v3_.y;  dst[1]=v3_.z;  dst[0]=v3_.w; }

// K1: LN(norm1) + in_proj (64 -> 256), split into xc (b,d,l layout) and silu(z) (p,d layout)
__global__ __launch_bounds__(256) void k1_ln_inproj(
    const float* __restrict__ xmag, const float* __restrict__ xph,
    const float* __restrict__ n1w_, const float* __restrict__ n1b_,
    const float* __restrict__ ipw_, float* __restrict__ ws)
{
  const int i = blockIdx.y;
  const float* xin = i ? xph : xmag;
  const float* n1w = n1w_ + i*CC;
  const float* n1b = n1b_ + i*CC;
  const float* ipw = ipw_ + i*2*DI*CC;
  float* xcin = ws + (size_t)i*ISTRIDE + OFF_XCIN;
  float* zbuf = ws + (size_t)i*ISTRIDE + OFF_Z;
  __shared__ float hn[CC];
  const int t = threadIdx.x;
  for(int pp=0; pp<8; ++pp){
    const int p = blockIdx.x*8 + pp;
    const int b = p >> 12, l = p & (LL-1);
    if(t < CC){
      float v = xin[p*CC + t];
      float s1 = wave_allsum(v);
      float s2 = wave_allsum(v*v);
      float mu = s1*(1.f/CC);
      float rs = rsqrtf(s2*(1.f/CC) - mu*mu + EPSF);
      hn[t] = (v-mu)*rs*n1w[t] + n1b[t];
    }
    __syncthreads();
    float acc = 0.f;
    #pragma unroll
    for(int c=0;c<CC;++c) acc += hn[c]*ipw[t*CC + c];
    if(t < DI){
      xcin[((size_t)(b*DI + t))*LL + l] = acc;
    } else {
      zbuf[(size_t)p*DI + (t-DI)] = acc * sigmoidf_(acc);   // silu
    }
    __syncthreads();
  }
}

// K2: depthwise 3x3 conv + silu; per (b,d) 64x64 tile via LDS; writes row-major and transposed
__global__ __launch_bounds__(256) void k2_dwconv(
    const float* __restrict__ cw_, float* __restrict__ ws)
{
  const int i = blockIdx.y;
  const int bd = blockIdx.x;            // b*DI + d
  const int d = bd & (DI-1);
  const float* cw = cw_ + i*DI*9 + d*9;
  const float* xcin  = ws + (size_t)i*ISTRIDE + OFF_XCIN  + (size_t)bd*LL;
  float* xconv  = ws + (size_t)i*ISTRIDE + OFF_XCONV  + (size_t)bd*LL;
  float* xconvT = ws + (size_t)i*ISTRIDE + OFF_XCONVT + (size_t)bd*LL;
  __shared__ float tin[64*65];
  __shared__ float tout[64*65];
  const int t = threadIdx.x;
  float w9[9];
  #pragma unroll
  for(int q=0;q<9;++q) w9[q] = cw[q];
  for(int idx=t; idx<4096; idx+=256)
    tin[(idx>>6)*65 + (idx&63)] = xcin[idx];
  __syncthreads();
  const int w = t & 63, hb = (t>>6)*16;
  #pragma unroll
  for(int r=0;r<16;++r){
    const int h = hb + r;
    float acc = 0.f;
    #pragma unroll
    for(int dy=0;dy<3;++dy){
      const int hh = h + dy - 1;
      if(hh>=0 && hh<64){
        #pragma unroll
        for(int dx=0;dx<3;++dx){
          const int ww = w + dx - 1;
          if(ww>=0 && ww<64) acc += tin[hh*65+ww]*w9[dy*3+dx];
        }
      }
    }
    const float o = acc * sigmoidf_(acc);  // silu
    tout[h*65+w] = o;
    xconv[h*64+w] = o;
  }
  __syncthreads();
  const int hcol = t & 63, wb = (t>>6)*16;
  #pragma unroll
  for(int r=0;r<16;++r){
    const int wp = wb + r;
    xconvT[wp*64 + hcol] = tout[hcol*65 + wp];   // stride-65 LDS read: conflict-free
  }
}

// K3a: x_dbl = x_proj(xs) -> (dts[4], Bs, Cs) per (b,k,scan-pos)
__global__ __launch_bounds__(256) void k3a_xproj(
    const float* __restrict__ xpw_, float* __restrict__ ws)
{
  const int i = blockIdx.z;
  const int b = blockIdx.y >> 2;
  const int k = blockIdx.y & 3;
  const int l = blockIdx.x*256 + threadIdx.x;
  const float* src = ws + (size_t)i*ISTRIDE + ((k&1)? OFF_XCONVT : OFF_XCONV) + (size_t)b*DI*LL;
  const int ridx = (k>=2) ? (LL-1-l) : l;
  const float* xpw = xpw_ + i*KK*6*DI + k*6*DI;
  float acc[6] = {0,0,0,0,0,0};
  for(int d=0; d<DI; ++d){
    const float xv = src[(size_t)d*LL + ridx];
    #pragma unroll
    for(int c=0;c<6;++c) acc[c] += xv * xpw[c*DI + d];
  }
  float* xdbl = ws + (size_t)i*ISTRIDE + OFF_XDBL + (size_t)(b*KK+k)*6*LL;
  #pragma unroll
  for(int c=0;c<6;++c) xdbl[(size_t)c*LL + l] = acc[c];
}

// K3b: paired fwd/bwd selective scan per (b, kpair, d). No atomics.
__global__ __launch_bounds__(256) void k3b_scan(
    const float* __restrict__ dtw_, const float* __restrict__ dtb_,
    const float* __restrict__ alog_, const float* __restrict__ Ds_,
    float* __restrict__ ws)
{
  const int gid = blockIdx.x;           // b*256 + kp*128 + d
  const int i = blockIdx.y;
  const int d  = gid & (DI-1);
  const int kp = (gid >> 7) & 1;        // 0: rows (k=0,2)  1: cols (k=1,3)
  const int b  = gid >> 8;
  const int t = threadIdx.x;
  float* base = ws + (size_t)i*ISTRIDE;
  const float* src = base + (kp? OFF_XCONVT : OFF_XCONV) + (size_t)(b*DI+d)*LL;
  float*       dst = base + (kp? OFF_YT    : OFF_Y    ) + (size_t)(b*DI+d)*LL;
  const float* xdF = base + OFF_XDBL + (size_t)(b*KK+kp  )*6*LL;   // k = kp
  const float* xdB = base + OFF_XDBL + (size_t)(b*KK+kp+2)*6*LL;   // k = kp+2
  const int kdF = kp*DI + d, kdB = (kp+2)*DI + d;
  const float4 wF = ((const float4*)dtw_)[i*KK*DI + kdF];
  const float4 wB = ((const float4*)dtw_)[i*KK*DI + kdB];
  const float biasF = dtb_[i*KK*DI + kdF], biasB = dtb_[i*KK*DI + kdB];
  const float AvF = -expf(alog_[i*KK*DI + kdF]);
  const float AvB = -expf(alog_[i*KK*DI + kdB]);
  const float Dsum = Ds_[i*KK*DI + kdF] + Ds_[i*KK*DI + kdB];
  const int l0 = t*16;          // this thread's contiguous chunk [l0, l0+16)
  const int s0 = LL - 16 - l0;  // backward direction's scan positions for chunk

  float vX[16], aF[16], bF[16], cF[16], aB[16], bB[16], cB[16];
  float pre[16], r0[16];
  LD16(vX, src + l0);

  // ---- forward (k = kp): scan position == l ----
  LD16(r0, xdF + 0*LL + l0);
  #pragma unroll
  for(int j=0;j<16;++j) pre[j] = biasF + wF.x*r0[j];
  LD16(r0, xdF + 1*LL + l0);
  #pragma unroll
  for(int j=0;j<16;++j) pre[j] += wF.y*r0[j];
  LD16(r0, xdF + 2*LL + l0);
  #pragma unroll
  for(int j=0;j<16;++j) pre[j] += wF.z*r0[j];
  LD16(r0, xdF + 3*LL + l0);
  #pragma unroll
  for(int j=0;j<16;++j) pre[j] += wF.w*r0[j];
  LD16(r0, xdF + 4*LL + l0);   // Bs
  float fA = 1.f, fB = 0.f;
  #pragma unroll
  for(int j=0;j<16;++j){
    const float delta = softplusf_(pre[j]);
    aF[j] = expf(delta*AvF);
    bF[j] = delta*r0[j]*vX[j];
    fB = fB*aF[j] + bF[j];
    fA *= aF[j];
  }
  LD16(cF, xdF + 5*LL + l0);   // Cs

  // ---- backward (k = kp+2): scan position s = LL-1-l, stored reversed ----
  LD16R(r0, xdB + 0*LL + s0);
  #pragma unroll
  for(int j=0;j<16;++j) pre[j] = biasB + wB.x*r0[j];
  LD16R(r0, xdB + 1*LL + s0);
  #pragma unroll
  for(int j=0;j<16;++j) pre[j] += wB.y*r0[j];
  LD16R(r0, xdB + 2*LL + s0);
  #pragma unroll
  for(int j=0;j<16;++j) pre[j] += wB.z*r0[j];
  LD16R(r0, xdB + 3*LL + s0);
  #pragma unroll
  for(int j=0;j<16;++j) pre[j] += wB.w*r0[j];
  LD16R(r0, xdB + 4*LL + s0);  // Bs (reversed into l-order)
  float gA = 1.f, gB = 0.f;
  #pragma unroll
  for(int j=15;j>=0;--j){
    const float delta = softplusf_(pre[j]);
    aB[j] = expf(delta*AvB);
    bB[j] = delta*r0[j]*vX[j];
    gB = gB*aB[j] + bB[j];
    gA *= aB[j];
  }
  LD16R(cB, xdB + 5*LL + s0);  // Cs (reversed into l-order)

  // ---- block-level scans: prefix (fwd) and suffix (bwd) over thread aggregates ----
  __shared__ float sAf[256], sBf[256], sAb[256], sBb[256];
  sAf[t]=fA; sBf[t]=fB; sAb[t]=gA; sBb[t]=gB;
  __syncthreads();
  #pragma unroll
  for(int off=1; off<256; off<<=1){
    float aL=1.f, bL=0.f, aR=1.f, bR=0.f;
    if(t>=off){ aL=sAf[t-off]; bL=sBf[t-off]; }
    if(t+off<256){ aR=sAb[t+off]; bR=sBb[t+off]; }
    __syncthreads();
    if(t>=off){ fB = bL*fA + fB; fA = aL*fA; sAf[t]=fA; sBf[t]=fB; }
    if(t+off<256){ gB = gA*bR + gB; gA = gA*aR; sAb[t]=gA; sBb[t]=gB; }
    __syncthreads();
  }
  float hf = (t>0)   ? sBf[t-1] : 0.f;   // state entering chunk from the left
  float hb = (t<255) ? sBb[t+1] : 0.f;   // state entering chunk from the right
  #pragma unroll
  for(int j=0;j<16;++j){
    hf = aF[j]*hf + bF[j];
    vX[j] = hf*cF[j] + Dsum*vX[j];       // fwd contribution + D terms
  }
  #pragma unroll
  for(int j=15;j>=0;--j){
    hb = aB[j]*hb + bB[j];
    vX[j] += hb*cB[j];                   // bwd contribution
  }
  float4* d4 = (float4*)(dst + l0);
  d4[0] = make_float4(vX[0],vX[1],vX[2],vX[3]);
  d4[1] = make_float4(vX[4],vX[5],vX[6],vX[7]);
  d4[2] = make_float4(vX[8],vX[9],vX[10],vX[11]);
  d4[3] = make_float4(vX[12],vX[13],vX[14],vX[15]);
}

// K3c: combine y + transpose(yT) into pixel-major ycomb[b][l][d].
// Block = (b, 16x16 spatial tile); loop d in chunks of 16 through LDS.
__global__ __launch_bounds__(256) void k3c_combine(float* __restrict__ ws)
{
  const int i = blockIdx.y;
  const int b = blockIdx.x >> 4;
  const int tile = blockIdx.x & 15;
  const int h0 = (tile >> 2) * 16, w0 = (tile & 3) * 16;
  const int t = threadIdx.x;
  float* base = ws + (size_t)i*ISTRIDE;
  const float* y  = base + OFF_Y;
  const float* yT = base + OFF_YT;
  float* ycomb = base + OFF_YCOMB;
  __shared__ float ytile[16*16*16];        // [dd][hi][wi]
  __shared__ float ytT[16*16*17];          // [dd][wi][hi+pad]
  const int r0 = t >> 4, c0 = t & 15;      // load-phase coords
  for(int dc=0; dc<8; ++dc){
    #pragma unroll 4
    for(int dd=0; dd<16; ++dd){
      const int d = dc*16 + dd;
      const size_t rb = (size_t)(b*DI + d)*LL;
      ytile[dd*256 + t] = y[rb + (size_t)(h0 + r0)*64 + (w0 + c0)];
      ytT[dd*272 + r0*17 + c0] = yT[rb + (size_t)(w0 + r0)*64 + (h0 + c0)];
    }
    __syncthreads();
    const int hi = t >> 4, wi = t & 15;
    const int l = (h0 + hi)*64 + (w0 + wi);
    float* outp = ycomb + ((size_t)(b*LL + l))*DI + dc*16;
    #pragma unroll
    for(int q=0;q<4;++q){
      float4 v;
      v.x = ytile[(4*q+0)*256 + t] + ytT[(4*q+0)*272 + wi*17 + hi];
      v.y = ytile[(4*q+1)*256 + t] + ytT[(4*q+1)*272 + wi*17 + hi];
      v.z = ytile[(4*q+2)*256 + t] + ytT[(4*q+2)*272 + wi*17 + hi];
      v.w = ytile[(4*q+3)*256 + t] + ytT[(4*q+3)*272 + wi*17 + hi];
      ((float4*)outp)[q] = v;
    }
    __syncthreads();
  }
}

// K0t: transpose f2w (64x256 row-major) -> f2wT (256x64) once per call
__global__ __launch_bounds__(256) void k0_transpose(
    const float* __restrict__ f2w_, float* __restrict__ ws)
{
  const int i = blockIdx.y;
  const int idx = blockIdx.x*256 + threadIdx.x;   // 0..16383
  const float v = f2w_[i*16384 + idx];
  const int o = idx >> 8, j = idx & 255;
  ws[(size_t)i*ISTRIDE + OFF_F2WT + (size_t)j*64 + o] = v;
}

// K4a: thread = pixel. LN(ycomb)*z (regs) -> out_proj (uniform scalar weights) -> +xin -> xnew.
__global__ __launch_bounds__(256, 2) void k4a_proj(
    const float* __restrict__ xmag, const float* __restrict__ xph,
    const float* __restrict__ onw_, const float* __restrict__ onb_,
    const float* __restrict__ opw_, float* __restrict__ ws)
{
  const int i = blockIdx.y;
  const float* xin = i ? xph : xmag;
  const float* onw = onw_ + i*DI;
  const float* onb = onb_ + i*DI;
  const float* opw = opw_ + i*CC*DI;
  float* base = ws + (size_t)i*ISTRIDE;
  const int p = blockIdx.x*256 + threadIdx.x;     // pixel 0..32767
  const float4* yc4 = (const float4*)(base + OFF_YCOMB + (size_t)p*DI);
  const float4* z4  = (const float4*)(base + OFF_Z     + (size_t)p*DI);
  float yv[DI];
  #pragma unroll
  for(int q=0;q<32;++q){
    float4 v = yc4[q];
    yv[4*q]=v.x; yv[4*q+1]=v.y; yv[4*q+2]=v.z; yv[4*q+3]=v.w;
  }
  float s1=0.f, s2=0.f;
  #pragma unroll
  for(int c=0;c<DI;++c){ s1 += yv[c]; s2 += yv[c]*yv[c]; }
  const float mu = s1*(1.f/DI);
  const float rs = rsqrtf(s2*(1.f/DI) - mu*mu + EPSF);
  #pragma unroll
  for(int q=0;q<32;++q){
    float4 zv = z4[q];
    yv[4*q]   = ((yv[4*q]  -mu)*rs*onw[4*q]  +onb[4*q]  )*zv.x;
    yv[4*q+1] = ((yv[4*q+1]-mu)*rs*onw[4*q+1]+onb[4*q+1])*zv.y;
    yv[4*q+2] = ((yv[4*q+2]-mu)*rs*onw[4*q+2]+onb[4*q+2])*zv.z;
    yv[4*q+3] = ((yv[4*q+3]-mu)*rs*onw[4*q+3]+onb[4*q+3])*zv.w;
  }
  float* xnew = base + OFF_XNEW + (size_t)p*CC;
  const float4* xi4 = (const float4*)(xin + (size_t)p*CC);
  for(int jc=0; jc<16; ++jc){            // 4 outputs per iteration (small I$ body)
    const float* w0 = opw + (jc*4+0)*DI;
    const float* w1 = opw + (jc*4+1)*DI;
    const float* w2 = opw + (jc*4+2)*DI;
    const float* w3 = opw + (jc*4+3)*DI;
    float a0=0.f,a1=0.f,a2=0.f,a3=0.f;
    #pragma unroll
    for(int c=0;c<DI;++c){
      const float yc = yv[c];
      a0 += yc*w0[c]; a1 += yc*w1[c]; a2 += yc*w2[c]; a3 += yc*w3[c];
    }
    const float4 xi = xi4[jc];
    ((float4*)xnew)[jc] = make_float4(xi.x+a0, xi.y+a1, xi.z+a2, xi.w+a3);
  }
}

// K4b: thread = pixel. LN2 (regs) -> fc1+GELU -> fc2 (both uniform contiguous scalar weights) -> residual.
__global__ __launch_bounds__(256, 2) void k4b_mlp(
    const float* __restrict__ n2w_, const float* __restrict__ n2b_,
    const float* __restrict__ f1w_, const float* __restrict__ f1b_,
    const float* __restrict__ f2b_, float* __restrict__ ws)
{
  const int i = blockIdx.y;
  const float* n2w = n2w_ + i*CC;
  const float* n2b = n2b_ + i*CC;
  const float* f1w = f1w_ + i*4*CC*CC;
  const float* f1b = f1b_ + i*4*CC;
  const float* f2b = f2b_ + i*CC;
  float* base = ws + (size_t)i*ISTRIDE;
  const float* f2wT = base + OFF_F2WT;
  const int p = blockIdx.x*256 + threadIdx.x;
  const float4* xn4 = (const float4*)(base + OFF_XNEW + (size_t)p*CC);
  float xnr[CC];
  #pragma unroll
  for(int q=0;q<16;++q){
    float4 v = xn4[q];
    xnr[4*q]=v.x; xnr[4*q+1]=v.y; xnr[4*q+2]=v.z; xnr[4*q+3]=v.w;
  }
  float s1=0.f, s2=0.f;
  #pragma unroll
  for(int c=0;c<CC;++c){ s1 += xnr[c]; s2 += xnr[c]*xnr[c]; }
  const float mu = s1*(1.f/CC);
  const float rs = rsqrtf(s2*(1.f/CC) - mu*mu + EPSF);
  float h2[CC];
  #pragma unroll
  for(int c=0;c<CC;++c) h2[c] = (xnr[c]-mu)*rs*n2w[c] + n2b[c];
  float acc[CC];
  #pragma unroll
  for(int o=0;o<CC;++o) acc[o] = f2b[o];
  for(int j=0;j<4*CC;++j){
    const float* w1r = f1w + j*CC;
    float g = f1b[j];
    #pragma unroll
    for(int c=0;c<CC;++c) g += h2[c]*w1r[c];
    g = geluf_(g);
    const float* w2r = f2wT + (size_t)j*CC;
    #pragma unroll
    for(int o=0;o<CC;++o) acc[o] += g*w2r[o];
  }
  float* sb = base + OFF_SB + (size_t)p*CC;
  #pragma unroll
  for(int q=0;q<16;++q)
    ((float4*)sb)[q] = make_float4(xnr[4*q]+acc[4*q], xnr[4*q+1]+acc[4*q+1],
                                   xnr[4*q+2]+acc[4*q+2], xnr[4*q+3]+acc[4*q+3]);
}

// K5: s = inst0 + inst1; write to both output halves
__global__ __launch_bounds__(256) void k5_final(
    const float* __restrict__ ws, float* __restrict__ out)
{
  const int idx = blockIdx.x*256 + threadIdx.x;
  const float v = ws[OFF_SB + idx] + ws[ISTRIDE + OFF_SB + idx];
  out[idx] = v;
  out[NPIX + idx] = v;
}

extern "C" void kernel_launch(void* const* d_in, const int* in_sizes, int n_in,
                              void* d_out, int out_size, void* d_ws, size_t ws_size,
                              hipStream_t stream)
{
  const float* mag  = (const float*)d_in[0];
  const float* ph   = (const float*)d_in[1];
  const float* n1w  = (const float*)d_in[2];
  const float* n1b  = (const float*)d_in[3];
  const float* ipw  = (const float*)d_in[4];
  const float* cw   = (const float*)d_in[5];
  const float* xpw  = (const float*)d_in[6];
  const float* dtw  = (const float*)d_in[7];
  const float* dtb  = (const float*)d_in[8];
  const float* alog = (const float*)d_in[9];
  const float* Ds   = (const float*)d_in[10];
  const float* onw  = (const float*)d_in[11];
  const float* onb  = (const float*)d_in[12];
  const float* opw  = (const float*)d_in[13];
  const float* n2w  = (const float*)d_in[14];
  const float* n2b  = (const float*)d_in[15];
  const float* f1w  = (const float*)d_in[16];
  const float* f1b  = (const float*)d_in[17];
  const float* f2w  = (const float*)d_in[18];
  const float* f2b  = (const float*)d_in[19];
  float* ws = (float*)d_ws;
  float* out = (float*)d_out;

  k1_ln_inproj<<<dim3(4096,2), 256, 0, stream>>>(mag, ph, n1w, n1b, ipw, ws);
  k2_dwconv   <<<dim3(1024,2), 256, 0, stream>>>(cw, ws);
  k3a_xproj   <<<dim3(16,32,2),256, 0, stream>>>(xpw, ws);
  k3b_scan    <<<dim3(2048,2), 256, 0, stream>>>(dtw, dtb, alog, Ds, ws);
  k3c_combine <<<dim3(128,2),  256, 0, stream>>>(ws);
  k0_transpose<<<dim3(64,2),   256, 0, stream>>>(f2w, ws);
  k4a_proj    <<<dim3(128,2),  256, 0, stream>>>(mag, ph, onw, onb, opw, ws);
  k4b_mlp     <<<dim3(128,2),  256, 0, stream>>>(n2w, n2b, f1w, f1b, f2b, ws);
  k5_final    <<<dim3(8192),   256, 0, stream>>>(ws, out);
}

// Round 5
// 936.000 us; speedup vs baseline: 3.0012x; 1.0778x over previous
//
#include <hip/hip_runtime.h>
#include <math.h>

// Problem constants
#define LL   4096      // H*W
#define DI   128       // 2*C
#define CC   64        // C
#define BB   8         // batch
#define KK   4         // scan directions
#define LB   32768     // pixels per instance
#define NPIX 2097152   // B*H*W*C elements of s
#define EPSF 1e-5f

// Workspace layout (floats, per instance)
#define OFF_XCIN   ((size_t)0)
#define OFF_XCONV  ((size_t)4194304)
#define OFF_XCONVT ((size_t)8388608)
#define OFF_Z      ((size_t)12582912)
#define OFF_Y      ((size_t)16777216)
#define OFF_YT     ((size_t)20971520)
#define OFF_XDBL   ((size_t)25165824)
#define ISTRIDE    ((size_t)25952256)   // floats per instance
// Aliases (lifetime-disjoint reuse):
#define OFF_YCOMBT OFF_XCIN             // xcin dead after k2; ycombT (d-major) by k3c
#define OFF_XNEW   OFF_YT               // yT dead after k3c; xnew (pixel-major) by k4a
#define OFF_SB     OFF_Y                // y dead after k3c; sbuf by k4b
#define OFF_F2WT   (OFF_Y + (size_t)2097152)  // f2w transposed (16384 floats)

__device__ __forceinline__ float sigmoidf_(float x){ return 1.f/(1.f+expf(-x)); }
__device__ __forceinline__ float softplusf_(float x){ return fmaxf(x,0.f) + log1pf(expf(-fabsf(x))); }
__device__ __forceinline__ float geluf_(float x){ return 0.5f*x*(1.f+erff(x*0.70710678118f)); }

#define LD16(dst, ptr) { const float4* p4_=(const float4*)(ptr);                 \
  float4 v0_=p4_[0], v1_=p4_[1], v2_=p4_[2], v3_=p4_[3];                         \
  dst[0]=v0_.x; dst[1]=v0_.y; dst[2]=v0_.z; dst[3]=v0_.w;                        \
  dst[4]=v1_.x; dst[5]=v1_.y; dst[6]=v1_.z; dst[7]=v1_.w;                        \
  dst[8]=v2_.x; dst[9]=v2_.y; dst[10]=v2_.z; dst[11]=v2_.w;                      \
  dst[12]=v3_.x; dst[13]=v3_.y; dst[14]=v3_.z; dst[15]=v3_.w; }
#define LD16R(dst, ptr) { const float4* p4_=(const float4*)(ptr);                \
  float4 v0_=p4_[0], v1_=p4_[1], v2_=p4_[2], v3_=p4_[3];                         \
  dst[15]=v0_.x; dst[14]=v0_.y; dst[13]=v0_.z; dst[12]=v0_.w;                    \
  dst[11]=v1_.x; dst[10]=v1_.y; dst[9]=v1_.z;  dst[8]=v1_.w;                     \
  dst[7]=v2_.x;  dst[6]=v2_.y;  dst[5]=v2_.z;  dst[4]=v2_.w;                     \
  dst[3]=v3_.x;  dst[2]=v3_.y;  dst[1]=v3_.z;  dst[0]=v3_.w; }

// K1 v2: lane = pixel. LN in registers; in_proj via wave-uniform s_load weight rows.
// Outputs: xc rows (b,d,l) coalesced per-j; z stored d-major zT[d][p].
__global__ __launch_bounds__(256) void k1_ln_inproj(
    const float* __restrict__ xmag, const float* __restrict__ xph,
    const float* __restrict__ n1w_, const float* __restrict__ n1b_,
    const float* __restrict__ ipw_, float* __restrict__ ws)
{
  const int i = blockIdx.y;
  const float* xin = i ? xph : xmag;
  const float* n1w = n1w_ + i*CC;
  const float* n1b = n1b_ + i*CC;
  const float* ipw = ipw_ + i*2*DI*CC;
  float* base = ws + (size_t)i*ISTRIDE;
  const int p = blockIdx.x*256 + threadIdx.x;   // pixel
  const int b = p >> 12, l = p & (LL-1);
  float hn[CC];
  LD16(hn, xin + (size_t)p*CC);
  LD16((hn+16), xin + (size_t)p*CC + 16);
  LD16((hn+32), xin + (size_t)p*CC + 32);
  LD16((hn+48), xin + (size_t)p*CC + 48);
  float s1=0.f, s2=0.f;
  #pragma unroll
  for(int c=0;c<CC;++c){ s1 += hn[c]; s2 += hn[c]*hn[c]; }
  const float mu = s1*(1.f/CC);
  const float rs = rsqrtf(s2*(1.f/CC) - mu*mu + EPSF);
  #pragma unroll
  for(int c=0;c<CC;++c) hn[c] = (hn[c]-mu)*rs*n1w[c] + n1b[c];
  float* xcb = base + OFF_XCIN + (size_t)b*DI*LL + l;
  #pragma unroll 2
  for(int j=0;j<DI;++j){
    const float* wr = ipw + j*CC;
    float acc = 0.f;
    #pragma unroll
    for(int c=0;c<CC;++c) acc += hn[c]*wr[c];
    xcb[(size_t)j*LL] = acc;
  }
  float* zT = base + OFF_Z;
  #pragma unroll 2
  for(int j=0;j<DI;++j){
    const float* wr = ipw + (DI+j)*CC;
    float acc = 0.f;
    #pragma unroll
    for(int c=0;c<CC;++c) acc += hn[c]*wr[c];
    zT[(size_t)j*LB + p] = acc * sigmoidf_(acc);   // silu, d-major
  }
}

// K2: depthwise 3x3 conv + silu; per (b,d) 64x64 tile via LDS; row-major + transposed out
__global__ __launch_bounds__(256) void k2_dwconv(
    const float* __restrict__ cw_, float* __restrict__ ws)
{
  const int i = blockIdx.y;
  const int bd = blockIdx.x;            // b*DI + d
  const int d = bd & (DI-1);
  const float* cw = cw_ + i*DI*9 + d*9;
  const float* xcin  = ws + (size_t)i*ISTRIDE + OFF_XCIN  + (size_t)bd*LL;
  float* xconv  = ws + (size_t)i*ISTRIDE + OFF_XCONV  + (size_t)bd*LL;
  float* xconvT = ws + (size_t)i*ISTRIDE + OFF_XCONVT + (size_t)bd*LL;
  __shared__ float tin[64*65];
  __shared__ float tout[64*65];
  const int t = threadIdx.x;
  float w9[9];
  #pragma unroll
  for(int q=0;q<9;++q) w9[q] = cw[q];
  for(int idx=t; idx<4096; idx+=256)
    tin[(idx>>6)*65 + (idx&63)] = xcin[idx];
  __syncthreads();
  const int w = t & 63, hb = (t>>6)*16;
  #pragma unroll
  for(int r=0;r<16;++r){
    const int h = hb + r;
    float acc = 0.f;
    #pragma unroll
    for(int dy=0;dy<3;++dy){
      const int hh = h + dy - 1;
      if(hh>=0 && hh<64){
        #pragma unroll
        for(int dx=0;dx<3;++dx){
          const int ww = w + dx - 1;
          if(ww>=0 && ww<64) acc += tin[hh*65+ww]*w9[dy*3+dx];
        }
      }
    }
    const float o = acc * sigmoidf_(acc);  // silu
    tout[h*65+w] = o;
    xconv[h*64+w] = o;
  }
  __syncthreads();
  const int hcol = t & 63, wb = (t>>6)*16;
  #pragma unroll
  for(int r=0;r<16;++r){
    const int wp = wb + r;
    xconvT[wp*64 + hcol] = tout[hcol*65 + wp];
  }
}

// K3a: x_dbl = x_proj(xs) -> (dts[4], Bs, Cs) per (b,k,scan-pos)
__global__ __launch_bounds__(256) void k3a_xproj(
    const float* __restrict__ xpw_, float* __restrict__ ws)
{
  const int i = blockIdx.z;
  const int b = blockIdx.y >> 2;
  const int k = blockIdx.y & 3;
  const int l = blockIdx.x*256 + threadIdx.x;
  const float* src = ws + (size_t)i*ISTRIDE + ((k&1)? OFF_XCONVT : OFF_XCONV) + (size_t)b*DI*LL;
  const int ridx = (k>=2) ? (LL-1-l) : l;
  const float* xpw = xpw_ + i*KK*6*DI + k*6*DI;
  float acc[6] = {0,0,0,0,0,0};
  for(int d=0; d<DI; ++d){
    const float xv = src[(size_t)d*LL + ridx];
    #pragma unroll
    for(int c=0;c<6;++c) acc[c] += xv * xpw[c*DI + d];
  }
  float* xdbl = ws + (size_t)i*ISTRIDE + OFF_XDBL + (size_t)(b*KK+k)*6*LL;
  #pragma unroll
  for(int c=0;c<6;++c) xdbl[(size_t)c*LL + l] = acc[c];
}

// K3b: paired fwd/bwd selective scan per (b, kpair, d). No atomics.
__global__ __launch_bounds__(256) void k3b_scan(
    const float* __restrict__ dtw_, const float* __restrict__ dtb_,
    const float* __restrict__ alog_, const float* __restrict__ Ds_,
    float* __restrict__ ws)
{
  const int gid = blockIdx.x;           // b*256 + kp*128 + d
  const int i = blockIdx.y;
  const int d  = gid & (DI-1);
  const int kp = (gid >> 7) & 1;
  const int b  = gid >> 8;
  const int t = threadIdx.x;
  float* base = ws + (size_t)i*ISTRIDE;
  const float* src = base + (kp? OFF_XCONVT : OFF_XCONV) + (size_t)(b*DI+d)*LL;
  float*       dst = base + (kp? OFF_YT    : OFF_Y    ) + (size_t)(b*DI+d)*LL;
  const float* xdF = base + OFF_XDBL + (size_t)(b*KK+kp  )*6*LL;
  const float* xdB = base + OFF_XDBL + (size_t)(b*KK+kp+2)*6*LL;
  const int kdF = kp*DI + d, kdB = (kp+2)*DI + d;
  const float4 wF = ((const float4*)dtw_)[i*KK*DI + kdF];
  const float4 wB = ((const float4*)dtw_)[i*KK*DI + kdB];
  const float biasF = dtb_[i*KK*DI + kdF], biasB = dtb_[i*KK*DI + kdB];
  const float AvF = -expf(alog_[i*KK*DI + kdF]);
  const float AvB = -expf(alog_[i*KK*DI + kdB]);
  const float Dsum = Ds_[i*KK*DI + kdF] + Ds_[i*KK*DI + kdB];
  const int l0 = t*16;
  const int s0 = LL - 16 - l0;

  float vX[16], aF[16], bF[16], cF[16], aB[16], bB[16], cB[16];
  float pre[16], r0[16];
  LD16(vX, src + l0);

  LD16(r0, xdF + 0*LL + l0);
  #pragma unroll
  for(int j=0;j<16;++j) pre[j] = biasF + wF.x*r0[j];
  LD16(r0, xdF + 1*LL + l0);
  #pragma unroll
  for(int j=0;j<16;++j) pre[j] += wF.y*r0[j];
  LD16(r0, xdF + 2*LL + l0);
  #pragma unroll
  for(int j=0;j<16;++j) pre[j] += wF.z*r0[j];
  LD16(r0, xdF + 3*LL + l0);
  #pragma unroll
  for(int j=0;j<16;++j) pre[j] += wF.w*r0[j];
  LD16(r0, xdF + 4*LL + l0);
  float fA = 1.f, fB = 0.f;
  #pragma unroll
  for(int j=0;j<16;++j){
    const float delta = softplusf_(pre[j]);
    aF[j] = expf(delta*AvF);
    bF[j] = delta*r0[j]*vX[j];
    fB = fB*aF[j] + bF[j];
    fA *= aF[j];
  }
  LD16(cF, xdF + 5*LL + l0);

  LD16R(r0, xdB + 0*LL + s0);
  #pragma unroll
  for(int j=0;j<16;++j) pre[j] = biasB + wB.x*r0[j];
  LD16R(r0, xdB + 1*LL + s0);
  #pragma unroll
  for(int j=0;j<16;++j) pre[j] += wB.y*r0[j];
  LD16R(r0, xdB + 2*LL + s0);
  #pragma unroll
  for(int j=0;j<16;++j) pre[j] += wB.z*r0[j];
  LD16R(r0, xdB + 3*LL + s0);
  #pragma unroll
  for(int j=0;j<16;++j) pre[j] += wB.w*r0[j];
  LD16R(r0, xdB + 4*LL + s0);
  float gA = 1.f, gB = 0.f;
  #pragma unroll
  for(int j=15;j>=0;--j){
    const float delta = softplusf_(pre[j]);
    aB[j] = expf(delta*AvB);
    bB[j] = delta*r0[j]*vX[j];
    gB = gB*aB[j] + bB[j];
    gA *= aB[j];
  }
  LD16R(cB, xdB + 5*LL + s0);

  __shared__ float sAf[256], sBf[256], sAb[256], sBb[256];
  sAf[t]=fA; sBf[t]=fB; sAb[t]=gA; sBb[t]=gB;
  __syncthreads();
  #pragma unroll
  for(int off=1; off<256; off<<=1){
    float aL=1.f, bL=0.f, aR=1.f, bR=0.f;
    if(t>=off){ aL=sAf[t-off]; bL=sBf[t-off]; }
    if(t+off<256){ aR=sAb[t+off]; bR=sBb[t+off]; }
    __syncthreads();
    if(t>=off){ fB = bL*fA + fB; fA = aL*fA; sAf[t]=fA; sBf[t]=fB; }
    if(t+off<256){ gB = gA*bR + gB; gA = gA*aR; sAb[t]=gA; sBb[t]=gB; }
    __syncthreads();
  }
  float hf = (t>0)   ? sBf[t-1] : 0.f;
  float hb = (t<255) ? sBb[t+1] : 0.f;
  #pragma unroll
  for(int j=0;j<16;++j){
    hf = aF[j]*hf + bF[j];
    vX[j] = hf*cF[j] + Dsum*vX[j];
  }
  #pragma unroll
  for(int j=15;j>=0;--j){
    hb = aB[j]*hb + bB[j];
    vX[j] += hb*cB[j];
  }
  float4* d4 = (float4*)(dst + l0);
  d4[0] = make_float4(vX[0],vX[1],vX[2],vX[3]);
  d4[1] = make_float4(vX[4],vX[5],vX[6],vX[7]);
  d4[2] = make_float4(vX[8],vX[9],vX[10],vX[11]);
  d4[3] = make_float4(vX[12],vX[13],vX[14],vX[15]);
}

// K3c v2: combine y + transpose(yT) into d-major ycombT[d][b*LL+l].
__global__ __launch_bounds__(256) void k3c_combine(float* __restrict__ ws)
{
  const int i = blockIdx.y;
  const int b = blockIdx.x >> 4;
  const int tile = blockIdx.x & 15;
  const int h0 = (tile >> 2) * 16, w0 = (tile & 3) * 16;
  const int t = threadIdx.x;
  float* base = ws + (size_t)i*ISTRIDE;
  const float* y  = base + OFF_Y;
  const float* yT = base + OFF_YT;
  float* ycT = base + OFF_YCOMBT;
  __shared__ float ytile[16*16*16];        // [dd][hi][wi]
  __shared__ float ytT[16*16*17];          // [dd][wi][hi+pad]
  const int r0 = t >> 4, c0 = t & 15;
  const int hi = t >> 4, wi = t & 15;
  const int l = (h0 + hi)*64 + (w0 + wi);
  for(int dc=0; dc<8; ++dc){
    #pragma unroll 4
    for(int dd=0; dd<16; ++dd){
      const int d = dc*16 + dd;
      const size_t rb = (size_t)(b*DI + d)*LL;
      ytile[dd*256 + t] = y[rb + (size_t)(h0 + r0)*64 + (w0 + c0)];
      ytT[dd*272 + r0*17 + c0] = yT[rb + (size_t)(w0 + r0)*64 + (h0 + c0)];
    }
    __syncthreads();
    #pragma unroll 4
    for(int dd=0; dd<16; ++dd){
      const int d = dc*16 + dd;
      ycT[(size_t)d*LB + b*LL + l] = ytile[dd*256 + t] + ytT[dd*272 + wi*17 + hi];
    }
    __syncthreads();
  }
}

// K0t: transpose f2w (64x256) -> f2wT (256x64)
__global__ __launch_bounds__(256) void k0_transpose(
    const float* __restrict__ f2w_, float* __restrict__ ws)
{
  const int i = blockIdx.y;
  const int idx = blockIdx.x*256 + threadIdx.x;
  const float v = f2w_[i*16384 + idx];
  const int o = idx >> 8, j = idx & 255;
  ws[(size_t)i*ISTRIDE + OFF_F2WT + (size_t)j*64 + o] = v;
}

// K4a v2: block = 4 waves = 2 pixel-groups x 2 K-chunks. lane = pixel.
// LN(DI=128) stats cross-chunk via LDS; out_proj partial dots reduced via LDS.
__global__ __launch_bounds__(256) void k4a_proj(
    const float* __restrict__ xmag, const float* __restrict__ xph,
    const float* __restrict__ onw_, const float* __restrict__ onb_,
    const float* __restrict__ opw_, float* __restrict__ ws)
{
  const int i = blockIdx.y;
  const float* xin = i ? xph : xmag;
  const float* onw = onw_ + i*DI;
  const float* onb = onb_ + i*DI;
  const float* opw = opw_ + i*CC*DI;
  float* base = ws + (size_t)i*ISTRIDE;
  const float* ycT = base + OFF_YCOMBT;
  const float* zT  = base + OFF_Z;
  const int t = threadIdx.x, lane = t & 63, wv = t >> 6;
  const int g = wv >> 1;
  const int ch = __builtin_amdgcn_readfirstlane(wv & 1);   // K-chunk id (SGPR)
  const int p = blockIdx.x*128 + g*64 + lane;              // pixel
  float yv[64];
  float s1=0.f, s2=0.f;
  #pragma unroll 8
  for(int c=0;c<64;++c){
    const float v = ycT[(size_t)(ch*64+c)*LB + p];
    yv[c]=v; s1+=v; s2+=v*v;
  }
  __shared__ float st[2][64][4];
  st[g][lane][ch*2]=s1; st[g][lane][ch*2+1]=s2;
  __syncthreads();
  const float S1 = st[g][lane][0]+st[g][lane][2];
  const float S2 = st[g][lane][1]+st[g][lane][3];
  const float mu = S1*(1.f/DI);
  const float rs = rsqrtf(S2*(1.f/DI) - mu*mu + EPSF);
  #pragma unroll 8
  for(int c=0;c<64;++c){
    const int d = ch*64+c;
    yv[c] = ((yv[c]-mu)*rs*onw[d] + onb[d]) * zT[(size_t)d*LB + p];
  }
  float acc[64];
  #pragma unroll 2
  for(int o=0;o<64;++o){
    const float* wr = opw + o*DI + ch*64;
    float a = 0.f;
    #pragma unroll
    for(int c=0;c<64;++c) a += yv[c]*wr[c];
    acc[o] = a;
  }
  __shared__ float ab[2][64*65];
  if(ch==0){
    #pragma unroll 8
    for(int o=0;o<64;++o) ab[g][lane*65+o] = acc[o];
  }
  __syncthreads();
  if(ch==1){
    #pragma unroll 8
    for(int o=0;o<64;++o) ab[g][lane*65+o] += acc[o];
  }
  __syncthreads();
  // store: thread -> (pixel t>>1, out-half (t&1)*32)
  const int pxl = t >> 1, oh = (t & 1)*32;
  const int gg = pxl >> 6, ll = pxl & 63;
  const int pg = blockIdx.x*128 + pxl;
  float* xnew = base + OFF_XNEW + (size_t)pg*CC + oh;
  const float* xi = xin + (size_t)pg*CC + oh;
  #pragma unroll
  for(int q=0;q<8;++q){
    float4 v;
    v.x = ab[gg][ll*65+oh+4*q  ] + xi[4*q  ];
    v.y = ab[gg][ll*65+oh+4*q+1] + xi[4*q+1];
    v.z = ab[gg][ll*65+oh+4*q+2] + xi[4*q+2];
    v.w = ab[gg][ll*65+oh+4*q+3] + xi[4*q+3];
    ((float4*)xnew)[q] = v;
  }
}

// K4b v2: block = 4 waves over the SAME 64 pixels; wave jc handles hidden units
// jc*64..+64. lane = pixel. fc1/fc2 weights via wave-uniform s_load. LDS reduce.
__global__ __launch_bounds__(256) void k4b_mlp(
    const float* __restrict__ n2w_, const float* __restrict__ n2b_,
    const float* __restrict__ f1w_, const float* __restrict__ f1b_,
    const float* __restrict__ f2b_, float* __restrict__ ws)
{
  const int i = blockIdx.y;
  const float* n2w = n2w_ + i*CC;
  const float* n2b = n2b_ + i*CC;
  const float* f1w = f1w_ + i*4*CC*CC;
  const float* f1b = f1b_ + i*4*CC;
  const float* f2b = f2b_ + i*CC;
  float* base = ws + (size_t)i*ISTRIDE;
  const float* f2wT = base + OFF_F2WT;
  const float* xnew = base + OFF_XNEW;
  const int t = threadIdx.x, lane = t & 63;
  const int jc = __builtin_amdgcn_readfirstlane(t >> 6);   // hidden-chunk id (SGPR)
  const int p = blockIdx.x*64 + lane;                      // pixel
  float h2[64];
  LD16(h2, xnew + (size_t)p*CC);
  LD16((h2+16), xnew + (size_t)p*CC + 16);
  LD16((h2+32), xnew + (size_t)p*CC + 32);
  LD16((h2+48), xnew + (size_t)p*CC + 48);
  float s1=0.f, s2=0.f;
  #pragma unroll
  for(int c=0;c<CC;++c){ s1 += h2[c]; s2 += h2[c]*h2[c]; }
  const float mu = s1*(1.f/CC);
  const float rs = rsqrtf(s2*(1.f/CC) - mu*mu + EPSF);
  #pragma unroll
  for(int c=0;c<CC;++c) h2[c] = (h2[c]-mu)*rs*n2w[c] + n2b[c];
  float acc[64];
  #pragma unroll
  for(int o=0;o<64;++o) acc[o] = 0.f;
  for(int jj=0;jj<64;++jj){
    const int j = jc*64 + jj;
    const float* w1r = f1w + j*CC;
    float gv = f1b[j];
    #pragma unroll
    for(int c=0;c<CC;++c) gv += h2[c]*w1r[c];
    gv = geluf_(gv);
    const float* w2r = f2wT + (size_t)j*CC;
    #pragma unroll
    for(int o=0;o<64;++o) acc[o] += gv*w2r[o];
  }
  __shared__ float ab[64*65];
  #pragma unroll
  for(int r=0;r<4;++r){
    if(jc==r){
      if(r==0){
        #pragma unroll 8
        for(int o=0;o<64;++o) ab[lane*65+o] = acc[o];
      } else {
        #pragma unroll 8
        for(int o=0;o<64;++o) ab[lane*65+o] += acc[o];
      }
    }
    __syncthreads();
  }
  // store: thread -> (pixel t>>2, out-quarter (t&3)*16); add f2b + residual
  const int pxl = t >> 2, oc = (t & 3)*16;
  const int pg = blockIdx.x*64 + pxl;
  const float* xr = xnew + (size_t)pg*CC + oc;
  float* sb = base + OFF_SB + (size_t)pg*CC + oc;
  #pragma unroll
  for(int q=0;q<4;++q){
    float4 v;
    v.x = ab[pxl*65+oc+4*q  ] + f2b[oc+4*q  ] + xr[4*q  ];
    v.y = ab[pxl*65+oc+4*q+1] + f2b[oc+4*q+1] + xr[4*q+1];
    v.z = ab[pxl*65+oc+4*q+2] + f2b[oc+4*q+2] + xr[4*q+2];
    v.w = ab[pxl*65+oc+4*q+3] + f2b[oc+4*q+3] + xr[4*q+3];
    ((float4*)sb)[q] = v;
  }
}

// K5: s = inst0 + inst1; write to both output halves
__global__ __launch_bounds__(256) void k5_final(
    const float* __restrict__ ws, float* __restrict__ out)
{
  const int idx = blockIdx.x*256 + threadIdx.x;
  const float v = ws[OFF_SB + idx] + ws[ISTRIDE + OFF_SB + idx];
  out[idx] = v;
  out[NPIX + idx] = v;
}

extern "C" void kernel_launch(void* const* d_in, const int* in_sizes, int n_in,
                              void* d_out, int out_size, void* d_ws, size_t ws_size,
                              hipStream_t stream)
{
  const float* mag  = (const float*)d_in[0];
  const float* ph   = (const float*)d_in[1];
  const float* n1w  = (const float*)d_in[2];
  const float* n1b  = (const float*)d_in[3];
  const float* ipw  = (const float*)d_in[4];
  const float* cw   = (const float*)d_in[5];
  const float* xpw  = (const float*)d_in[6];
  const float* dtw  = (const float*)d_in[7];
  const float* dtb  = (const float*)d_in[8];
  const float* alog = (const float*)d_in[9];
  const float* Ds   = (const float*)d_in[10];
  const float* onw  = (const float*)d_in[11];
  const float* onb  = (const float*)d_in[12];
  const float* opw  = (const float*)d_in[13];
  const float* n2w  = (const float*)d_in[14];
  const float* n2b  = (const float*)d_in[15];
  const float* f1w  = (const float*)d_in[16];
  const float* f1b  = (const float*)d_in[17];
  const float* f2w  = (const float*)d_in[18];
  const float* f2b  = (const float*)d_in[19];
  float* ws = (float*)d_ws;
  float* out = (float*)d_out;

  k1_ln_inproj<<<dim3(128,2),  256, 0, stream>>>(mag, ph, n1w, n1b, ipw, ws);
  k2_dwconv   <<<dim3(1024,2), 256, 0, stream>>>(cw, ws);
  k3a_xproj   <<<dim3(16,32,2),256, 0, stream>>>(xpw, ws);
  k3b_scan    <<<dim3(2048,2), 256, 0, stream>>>(dtw, dtb, alog, Ds, ws);
  k3c_combine <<<dim3(128,2),  256, 0, stream>>>(ws);
  k0_transpose<<<dim3(64,2),   256, 0, stream>>>(f2w, ws);
  k4a_proj    <<<dim3(256,2),  256, 0, stream>>>(mag, ph, onw, onb, opw, ws);
  k4b_mlp     <<<dim3(512,2),  256, 0, stream>>>(n2w, n2b, f1w, f1b, f2b, ws);
  k5_final    <<<dim3(8192),   256, 0, stream>>>(ws, out);
}

// Round 6
// 930.519 us; speedup vs baseline: 3.0189x; 1.0059x over previous
//
#include <hip/hip_runtime.h>
#include <math.h>

// Problem constants
#define LL   4096      // H*W
#define DI   128       // 2*C
#define CC   64        // C
#define BB   8         // batch
#define KK   4         // scan directions
#define LB   32768     // pixels per instance
#define NPIX 2097152   // B*H*W*C elements of s
#define EPSF 1e-5f

// Workspace layout (floats, per instance)
#define OFF_XCIN   ((size_t)0)
#define OFF_XCONV  ((size_t)4194304)
#define OFF_XCONVT ((size_t)8388608)
#define OFF_Z      ((size_t)12582912)
#define OFF_Y      ((size_t)16777216)
#define OFF_YT     ((size_t)20971520)
#define OFF_XDBL   ((size_t)25165824)
#define ISTRIDE    ((size_t)25952256)   // floats per instance
// Aliases (lifetime-disjoint reuse):
#define OFF_YCOMBT OFF_XCIN             // xcin dead after k2; ycombT (d-major) by k3c
#define OFF_XNEW   OFF_YT               // yT dead after k3c; xnew (pixel-major) by k4a
#define OFF_SB     OFF_Y                // y dead after k3c; sbuf by k4b
#define OFF_F2WT   (OFF_Y + (size_t)2097152)  // f2w transposed (16384 floats)

__device__ __forceinline__ float sigmoidf_(float x){ return 1.f/(1.f+expf(-x)); }
__device__ __forceinline__ float softplusf_(float x){ return fmaxf(x,0.f) + log1pf(expf(-fabsf(x))); }
__device__ __forceinline__ float geluf_(float x){ return 0.5f*x*(1.f+erff(x*0.70710678118f)); }

#define LD16(dst, ptr) { const float4* p4_=(const float4*)(ptr);                 \
  float4 v0_=p4_[0], v1_=p4_[1], v2_=p4_[2], v3_=p4_[3];                         \
  dst[0]=v0_.x; dst[1]=v0_.y; dst[2]=v0_.z; dst[3]=v0_.w;                        \
  dst[4]=v1_.x; dst[5]=v1_.y; dst[6]=v1_.z; dst[7]=v1_.w;                        \
  dst[8]=v2_.x; dst[9]=v2_.y; dst[10]=v2_.z; dst[11]=v2_.w;                      \
  dst[12]=v3_.x; dst[13]=v3_.y; dst[14]=v3_.z; dst[15]=v3_.w; }
#define LD16R(dst, ptr) { const float4* p4_=(const float4*)(ptr);                \
  float4 v0_=p4_[0], v1_=p4_[1], v2_=p4_[2], v3_=p4_[3];                         \
  dst[15]=v0_.x; dst[14]=v0_.y; dst[13]=v0_.z; dst[12]=v0_.w;                    \
  dst[11]=v1_.x; dst[10]=v1_.y; dst[9]=v1_.z;  dst[8]=v1_.w;                     \
  dst[7]=v2_.x;  dst[6]=v2_.y;  dst[5]=v2_.z;  dst[4]=v2_.w;                     \
  dst[3]=v3_.x;  dst[2]=v3_.y;  dst[1]=v3_.z;  dst[0]=v3_.w; }

// K1 v3: block = 4 waves over the SAME 64 pixels (lane = pixel). Wave ch handles a
// 64-row chunk of the 256 in_proj outputs (ch 0-1: xc, ch 2-3: z). LN computed
// redundantly per wave in registers; weights wave-uniform (s_load broadcast).
__global__ __launch_bounds__(256) void k1_ln_inproj(
    const float* __restrict__ xmag, const float* __restrict__ xph,
    const float* __restrict__ n1w_, const float* __restrict__ n1b_,
    const float* __restrict__ ipw_, float* __restrict__ ws)
{
  const int i = blockIdx.y;
  const float* xin = i ? xph : xmag;
  const float* n1w = n1w_ + i*CC;
  const float* n1b = n1b_ + i*CC;
  const float* ipw = ipw_ + i*2*DI*CC;
  float* base = ws + (size_t)i*ISTRIDE;
  const int t = threadIdx.x, lane = t & 63;
  const int ch = __builtin_amdgcn_readfirstlane(t >> 6);   // output-chunk id (SGPR)
  const int p = blockIdx.x*64 + lane;                      // pixel
  const int b = p >> 12, l = p & (LL-1);
  float hn[CC];
  LD16(hn, xin + (size_t)p*CC);
  LD16((hn+16), xin + (size_t)p*CC + 16);
  LD16((hn+32), xin + (size_t)p*CC + 32);
  LD16((hn+48), xin + (size_t)p*CC + 48);
  float s1=0.f, s2=0.f;
  #pragma unroll
  for(int c=0;c<CC;++c){ s1 += hn[c]; s2 += hn[c]*hn[c]; }
  const float mu = s1*(1.f/CC);
  const float rs = rsqrtf(s2*(1.f/CC) - mu*mu + EPSF);
  #pragma unroll
  for(int c=0;c<CC;++c) hn[c] = (hn[c]-mu)*rs*n1w[c] + n1b[c];
  if(ch < 2){
    float* xcb = base + OFF_XCIN + (size_t)b*DI*LL + l;
    #pragma unroll 2
    for(int jj=0;jj<64;++jj){
      const int j = ch*64 + jj;
      const float* wr = ipw + j*CC;
      float acc = 0.f;
      #pragma unroll
      for(int c=0;c<CC;++c) acc += hn[c]*wr[c];
      xcb[(size_t)j*LL] = acc;
    }
  } else {
    float* zT = base + OFF_Z;
    #pragma unroll 2
    for(int jj=0;jj<64;++jj){
      const int d = (ch-2)*64 + jj;
      const float* wr = ipw + (DI+d)*CC;
      float acc = 0.f;
      #pragma unroll
      for(int c=0;c<CC;++c) acc += hn[c]*wr[c];
      zT[(size_t)d*LB + p] = acc * sigmoidf_(acc);   // silu, d-major
    }
  }
}

// K2: depthwise 3x3 conv + silu; per (b,d) 64x64 tile via LDS; row-major + transposed out
__global__ __launch_bounds__(256) void k2_dwconv(
    const float* __restrict__ cw_, float* __restrict__ ws)
{
  const int i = blockIdx.y;
  const int bd = blockIdx.x;            // b*DI + d
  const int d = bd & (DI-1);
  const float* cw = cw_ + i*DI*9 + d*9;
  const float* xcin  = ws + (size_t)i*ISTRIDE + OFF_XCIN  + (size_t)bd*LL;
  float* xconv  = ws + (size_t)i*ISTRIDE + OFF_XCONV  + (size_t)bd*LL;
  float* xconvT = ws + (size_t)i*ISTRIDE + OFF_XCONVT + (size_t)bd*LL;
  __shared__ float tin[64*65];
  __shared__ float tout[64*65];
  const int t = threadIdx.x;
  float w9[9];
  #pragma unroll
  for(int q=0;q<9;++q) w9[q] = cw[q];
  for(int idx=t; idx<4096; idx+=256)
    tin[(idx>>6)*65 + (idx&63)] = xcin[idx];
  __syncthreads();
  const int w = t & 63, hb = (t>>6)*16;
  #pragma unroll
  for(int r=0;r<16;++r){
    const int h = hb + r;
    float acc = 0.f;
    #pragma unroll
    for(int dy=0;dy<3;++dy){
      const int hh = h + dy - 1;
      if(hh>=0 && hh<64){
        #pragma unroll
        for(int dx=0;dx<3;++dx){
          const int ww = w + dx - 1;
          if(ww>=0 && ww<64) acc += tin[hh*65+ww]*w9[dy*3+dx];
        }
      }
    }
    const float o = acc * sigmoidf_(acc);  // silu
    tout[h*65+w] = o;
    xconv[h*64+w] = o;
  }
  __syncthreads();
  const int hcol = t & 63, wb = (t>>6)*16;
  #pragma unroll
  for(int r=0;r<16;++r){
    const int wp = wb + r;
    xconvT[wp*64 + hcol] = tout[hcol*65 + wp];
  }
}

// K3a: x_dbl = x_proj(xs) -> (dts[4], Bs, Cs) per (b,k,scan-pos)
__global__ __launch_bounds__(256) void k3a_xproj(
    const float* __restrict__ xpw_, float* __restrict__ ws)
{
  const int i = blockIdx.z;
  const int b = blockIdx.y >> 2;
  const int k = blockIdx.y & 3;
  const int l = blockIdx.x*256 + threadIdx.x;
  const float* src = ws + (size_t)i*ISTRIDE + ((k&1)? OFF_XCONVT : OFF_XCONV) + (size_t)b*DI*LL;
  const int ridx = (k>=2) ? (LL-1-l) : l;
  const float* xpw = xpw_ + i*KK*6*DI + k*6*DI;
  float acc[6] = {0,0,0,0,0,0};
  for(int d=0; d<DI; ++d){
    const float xv = src[(size_t)d*LL + ridx];
    #pragma unroll
    for(int c=0;c<6;++c) acc[c] += xv * xpw[c*DI + d];
  }
  float* xdbl = ws + (size_t)i*ISTRIDE + OFF_XDBL + (size_t)(b*KK+k)*6*LL;
  #pragma unroll
  for(int c=0;c<6;++c) xdbl[(size_t)c*LL + l] = acc[c];
}

// K3b: paired fwd/bwd selective scan per (b, kpair, d). No atomics.
__global__ __launch_bounds__(256) void k3b_scan(
    const float* __restrict__ dtw_, const float* __restrict__ dtb_,
    const float* __restrict__ alog_, const float* __restrict__ Ds_,
    float* __restrict__ ws)
{
  const int gid = blockIdx.x;           // b*256 + kp*128 + d
  const int i = blockIdx.y;
  const int d  = gid & (DI-1);
  const int kp = (gid >> 7) & 1;
  const int b  = gid >> 8;
  const int t = threadIdx.x;
  float* base = ws + (size_t)i*ISTRIDE;
  const float* src = base + (kp? OFF_XCONVT : OFF_XCONV) + (size_t)(b*DI+d)*LL;
  float*       dst = base + (kp? OFF_YT    : OFF_Y    ) + (size_t)(b*DI+d)*LL;
  const float* xdF = base + OFF_XDBL + (size_t)(b*KK+kp  )*6*LL;
  const float* xdB = base + OFF_XDBL + (size_t)(b*KK+kp+2)*6*LL;
  const int kdF = kp*DI + d, kdB = (kp+2)*DI + d;
  const float4 wF = ((const float4*)dtw_)[i*KK*DI + kdF];
  const float4 wB = ((const float4*)dtw_)[i*KK*DI + kdB];
  const float biasF = dtb_[i*KK*DI + kdF], biasB = dtb_[i*KK*DI + kdB];
  const float AvF = -expf(alog_[i*KK*DI + kdF]);
  const float AvB = -expf(alog_[i*KK*DI + kdB]);
  const float Dsum = Ds_[i*KK*DI + kdF] + Ds_[i*KK*DI + kdB];
  const int l0 = t*16;
  const int s0 = LL - 16 - l0;

  float vX[16], aF[16], bF[16], cF[16], aB[16], bB[16], cB[16];
  float pre[16], r0[16];
  LD16(vX, src + l0);

  LD16(r0, xdF + 0*LL + l0);
  #pragma unroll
  for(int j=0;j<16;++j) pre[j] = biasF + wF.x*r0[j];
  LD16(r0, xdF + 1*LL + l0);
  #pragma unroll
  for(int j=0;j<16;++j) pre[j] += wF.y*r0[j];
  LD16(r0, xdF + 2*LL + l0);
  #pragma unroll
  for(int j=0;j<16;++j) pre[j] += wF.z*r0[j];
  LD16(r0, xdF + 3*LL + l0);
  #pragma unroll
  for(int j=0;j<16;++j) pre[j] += wF.w*r0[j];
  LD16(r0, xdF + 4*LL + l0);
  float fA = 1.f, fB = 0.f;
  #pragma unroll
  for(int j=0;j<16;++j){
    const float delta = softplusf_(pre[j]);
    aF[j] = expf(delta*AvF);
    bF[j] = delta*r0[j]*vX[j];
    fB = fB*aF[j] + bF[j];
    fA *= aF[j];
  }
  LD16(cF, xdF + 5*LL + l0);

  LD16R(r0, xdB + 0*LL + s0);
  #pragma unroll
  for(int j=0;j<16;++j) pre[j] = biasB + wB.x*r0[j];
  LD16R(r0, xdB + 1*LL + s0);
  #pragma unroll
  for(int j=0;j<16;++j) pre[j] += wB.y*r0[j];
  LD16R(r0, xdB + 2*LL + s0);
  #pragma unroll
  for(int j=0;j<16;++j) pre[j] += wB.z*r0[j];
  LD16R(r0, xdB + 3*LL + s0);
  #pragma unroll
  for(int j=0;j<16;++j) pre[j] += wB.w*r0[j];
  LD16R(r0, xdB + 4*LL + s0);
  float gA = 1.f, gB = 0.f;
  #pragma unroll
  for(int j=15;j>=0;--j){
    const float delta = softplusf_(pre[j]);
    aB[j] = expf(delta*AvB);
    bB[j] = delta*r0[j]*vX[j];
    gB = gB*aB[j] + bB[j];
    gA *= aB[j];
  }
  LD16R(cB, xdB + 5*LL + s0);

  __shared__ float sAf[256], sBf[256], sAb[256], sBb[256];
  sAf[t]=fA; sBf[t]=fB; sAb[t]=gA; sBb[t]=gB;
  __syncthreads();
  #pragma unroll
  for(int off=1; off<256; off<<=1){
    float aL=1.f, bL=0.f, aR=1.f, bR=0.f;
    if(t>=off){ aL=sAf[t-off]; bL=sBf[t-off]; }
    if(t+off<256){ aR=sAb[t+off]; bR=sBb[t+off]; }
    __syncthreads();
    if(t>=off){ fB = bL*fA + fB; fA = aL*fA; sAf[t]=fA; sBf[t]=fB; }
    if(t+off<256){ gB = gA*bR + gB; gA = gA*aR; sAb[t]=gA; sBb[t]=gB; }
    __syncthreads();
  }
  float hf = (t>0)   ? sBf[t-1] : 0.f;
  float hb = (t<255) ? sBb[t+1] : 0.f;
  #pragma unroll
  for(int j=0;j<16;++j){
    hf = aF[j]*hf + bF[j];
    vX[j] = hf*cF[j] + Dsum*vX[j];
  }
  #pragma unroll
  for(int j=15;j>=0;--j){
    hb = aB[j]*hb + bB[j];
    vX[j] += hb*cB[j];
  }
  float4* d4 = (float4*)(dst + l0);
  d4[0] = make_float4(vX[0],vX[1],vX[2],vX[3]);
  d4[1] = make_float4(vX[4],vX[5],vX[6],vX[7]);
  d4[2] = make_float4(vX[8],vX[9],vX[10],vX[11]);
  d4[3] = make_float4(vX[12],vX[13],vX[14],vX[15]);
}

// K3c: combine y + transpose(yT) into d-major ycombT[d][b*LL+l].
__global__ __launch_bounds__(256) void k3c_combine(float* __restrict__ ws)
{
  const int i = blockIdx.y;
  const int b = blockIdx.x >> 4;
  const int tile = blockIdx.x & 15;
  const int h0 = (tile >> 2) * 16, w0 = (tile & 3) * 16;
  const int t = threadIdx.x;
  float* base = ws + (size_t)i*ISTRIDE;
  const float* y  = base + OFF_Y;
  const float* yT = base + OFF_YT;
  float* ycT = base + OFF_YCOMBT;
  __shared__ float ytile[16*16*16];        // [dd][hi][wi]
  __shared__ float ytT[16*16*17];          // [dd][wi][hi+pad]
  const int r0 = t >> 4, c0 = t & 15;
  const int hi = t >> 4, wi = t & 15;
  const int l = (h0 + hi)*64 + (w0 + wi);
  for(int dc=0; dc<8; ++dc){
    #pragma unroll 4
    for(int dd=0; dd<16; ++dd){
      const int d = dc*16 + dd;
      const size_t rb = (size_t)(b*DI + d)*LL;
      ytile[dd*256 + t] = y[rb + (size_t)(h0 + r0)*64 + (w0 + c0)];
      ytT[dd*272 + r0*17 + c0] = yT[rb + (size_t)(w0 + r0)*64 + (h0 + c0)];
    }
    __syncthreads();
    #pragma unroll 4
    for(int dd=0; dd<16; ++dd){
      const int d = dc*16 + dd;
      ycT[(size_t)d*LB + b*LL + l] = ytile[dd*256 + t] + ytT[dd*272 + wi*17 + hi];
    }
    __syncthreads();
  }
}

// K0t: transpose f2w (64x256) -> f2wT (256x64)
__global__ __launch_bounds__(256) void k0_transpose(
    const float* __restrict__ f2w_, float* __restrict__ ws)
{
  const int i = blockIdx.y;
  const int idx = blockIdx.x*256 + threadIdx.x;
  const float v = f2w_[i*16384 + idx];
  const int o = idx >> 8, j = idx & 255;
  ws[(size_t)i*ISTRIDE + OFF_F2WT + (size_t)j*64 + o] = v;
}

// K4a: block = 4 waves = 2 pixel-groups x 2 K-chunks. lane = pixel.
__global__ __launch_bounds__(256) void k4a_proj(
    const float* __restrict__ xmag, const float* __restrict__ xph,
    const float* __restrict__ onw_, const float* __restrict__ onb_,
    const float* __restrict__ opw_, float* __restrict__ ws)
{
  const int i = blockIdx.y;
  const float* xin = i ? xph : xmag;
  const float* onw = onw_ + i*DI;
  const float* onb = onb_ + i*DI;
  const float* opw = opw_ + i*CC*DI;
  float* base = ws + (size_t)i*ISTRIDE;
  const float* ycT = base + OFF_YCOMBT;
  const float* zT  = base + OFF_Z;
  const int t = threadIdx.x, lane = t & 63, wv = t >> 6;
  const int g = wv >> 1;
  const int ch = __builtin_amdgcn_readfirstlane(wv & 1);   // K-chunk id (SGPR)
  const int p = blockIdx.x*128 + g*64 + lane;              // pixel
  float yv[64];
  float s1=0.f, s2=0.f;
  #pragma unroll 8
  for(int c=0;c<64;++c){
    const float v = ycT[(size_t)(ch*64+c)*LB + p];
    yv[c]=v; s1+=v; s2+=v*v;
  }
  __shared__ float st[2][64][4];
  st[g][lane][ch*2]=s1; st[g][lane][ch*2+1]=s2;
  __syncthreads();
  const float S1 = st[g][lane][0]+st[g][lane][2];
  const float S2 = st[g][lane][1]+st[g][lane][3];
  const float mu = S1*(1.f/DI);
  const float rs = rsqrtf(S2*(1.f/DI) - mu*mu + EPSF);
  #pragma unroll 8
  for(int c=0;c<64;++c){
    const int d = ch*64+c;
    yv[c] = ((yv[c]-mu)*rs*onw[d] + onb[d]) * zT[(size_t)d*LB + p];
  }
  float acc[64];
  #pragma unroll 2
  for(int o=0;o<64;++o){
    const float* wr = opw + o*DI + ch*64;
    float a = 0.f;
    #pragma unroll
    for(int c=0;c<64;++c) a += yv[c]*wr[c];
    acc[o] = a;
  }
  __shared__ float ab[2][64*65];
  if(ch==0){
    #pragma unroll 8
    for(int o=0;o<64;++o) ab[g][lane*65+o] = acc[o];
  }
  __syncthreads();
  if(ch==1){
    #pragma unroll 8
    for(int o=0;o<64;++o) ab[g][lane*65+o] += acc[o];
  }
  __syncthreads();
  const int pxl = t >> 1, oh = (t & 1)*32;
  const int gg = pxl >> 6, ll = pxl & 63;
  const int pg = blockIdx.x*128 + pxl;
  float* xnew = base + OFF_XNEW + (size_t)pg*CC + oh;
  const float* xi = xin + (size_t)pg*CC + oh;
  #pragma unroll
  for(int q=0;q<8;++q){
    float4 v;
    v.x = ab[gg][ll*65+oh+4*q  ] + xi[4*q  ];
    v.y = ab[gg][ll*65+oh+4*q+1] + xi[4*q+1];
    v.z = ab[gg][ll*65+oh+4*q+2] + xi[4*q+2];
    v.w = ab[gg][ll*65+oh+4*q+3] + xi[4*q+3];
    ((float4*)xnew)[q] = v;
  }
}

// K4b: block = 4 waves over the SAME 64 pixels; wave jc handles hidden units jc*64..+64.
__global__ __launch_bounds__(256) void k4b_mlp(
    const float* __restrict__ n2w_, const float* __restrict__ n2b_,
    const float* __restrict__ f1w_, const float* __restrict__ f1b_,
    const float* __restrict__ f2b_, float* __restrict__ ws)
{
  const int i = blockIdx.y;
  const float* n2w = n2w_ + i*CC;
  const float* n2b = n2b_ + i*CC;
  const float* f1w = f1w_ + i*4*CC*CC;
  const float* f1b = f1b_ + i*4*CC;
  const float* f2b = f2b_ + i*CC;
  float* base = ws + (size_t)i*ISTRIDE;
  const float* f2wT = base + OFF_F2WT;
  const float* xnew = base + OFF_XNEW;
  const int t = threadIdx.x, lane = t & 63;
  const int jc = __builtin_amdgcn_readfirstlane(t >> 6);   // hidden-chunk id (SGPR)
  const int p = blockIdx.x*64 + lane;                      // pixel
  float h2[64];
  LD16(h2, xnew + (size_t)p*CC);
  LD16((h2+16), xnew + (size_t)p*CC + 16);
  LD16((h2+32), xnew + (size_t)p*CC + 32);
  LD16((h2+48), xnew + (size_t)p*CC + 48);
  float s1=0.f, s2=0.f;
  #pragma unroll
  for(int c=0;c<CC;++c){ s1 += h2[c]; s2 += h2[c]*h2[c]; }
  const float mu = s1*(1.f/CC);
  const float rs = rsqrtf(s2*(1.f/CC) - mu*mu + EPSF);
  #pragma unroll
  for(int c=0;c<CC;++c) h2[c] = (h2[c]-mu)*rs*n2w[c] + n2b[c];
  float acc[64];
  #pragma unroll
  for(int o=0;o<64;++o) acc[o] = 0.f;
  for(int jj=0;jj<64;++jj){
    const int j = jc*64 + jj;
    const float* w1r = f1w + j*CC;
    float gv = f1b[j];
    #pragma unroll
    for(int c=0;c<CC;++c) gv += h2[c]*w1r[c];
    gv = geluf_(gv);
    const float* w2r = f2wT + (size_t)j*CC;
    #pragma unroll
    for(int o=0;o<64;++o) acc[o] += gv*w2r[o];
  }
  __shared__ float ab[64*65];
  #pragma unroll
  for(int r=0;r<4;++r){
    if(jc==r){
      if(r==0){
        #pragma unroll 8
        for(int o=0;o<64;++o) ab[lane*65+o] = acc[o];
      } else {
        #pragma unroll 8
        for(int o=0;o<64;++o) ab[lane*65+o] += acc[o];
      }
    }
    __syncthreads();
  }
  const int pxl = t >> 2, oc = (t & 3)*16;
  const int pg = blockIdx.x*64 + pxl;
  const float* xr = xnew + (size_t)pg*CC + oc;
  float* sb = base + OFF_SB + (size_t)pg*CC + oc;
  #pragma unroll
  for(int q=0;q<4;++q){
    float4 v;
    v.x = ab[pxl*65+oc+4*q  ] + f2b[oc+4*q  ] + xr[4*q  ];
    v.y = ab[pxl*65+oc+4*q+1] + f2b[oc+4*q+1] + xr[4*q+1];
    v.z = ab[pxl*65+oc+4*q+2] + f2b[oc+4*q+2] + xr[4*q+2];
    v.w = ab[pxl*65+oc+4*q+3] + f2b[oc+4*q+3] + xr[4*q+3];
    ((float4*)sb)[q] = v;
  }
}

// K5: s = inst0 + inst1; write to both output halves
__global__ __launch_bounds__(256) void k5_final(
    const float* __restrict__ ws, float* __restrict__ out)
{
  const int idx = blockIdx.x*256 + threadIdx.x;
  const float v = ws[OFF_SB + idx] + ws[ISTRIDE + OFF_SB + idx];
  out[idx] = v;
  out[NPIX + idx] = v;
}

extern "C" void kernel_launch(void* const* d_in, const int* in_sizes, int n_in,
                              void* d_out, int out_size, void* d_ws, size_t ws_size,
                              hipStream_t stream)
{
  const float* mag  = (const float*)d_in[0];
  const float* ph   = (const float*)d_in[1];
  const float* n1w  = (const float*)d_in[2];
  const float* n1b  = (const float*)d_in[3];
  const float* ipw  = (const float*)d_in[4];
  const float* cw   = (const float*)d_in[5];
  const float* xpw  = (const float*)d_in[6];
  const float* dtw  = (const float*)d_in[7];
  const float* dtb  = (const float*)d_in[8];
  const float* alog = (const float*)d_in[9];
  const float* Ds   = (const float*)d_in[10];
  const float* onw  = (const float*)d_in[11];
  const float* onb  = (const float*)d_in[12];
  const float* opw  = (const float*)d_in[13];
  const float* n2w  = (const float*)d_in[14];
  const float* n2b  = (const float*)d_in[15];
  const float* f1w  = (const float*)d_in[16];
  const float* f1b  = (const float*)d_in[17];
  const float* f2w  = (const float*)d_in[18];
  const float* f2b  = (const float*)d_in[19];
  float* ws = (float*)d_ws;
  float* out = (float*)d_out;

  k1_ln_inproj<<<dim3(512,2),  256, 0, stream>>>(mag, ph, n1w, n1b, ipw, ws);
  k2_dwconv   <<<dim3(1024,2), 256, 0, stream>>>(cw, ws);
  k3a_xproj   <<<dim3(16,32,2),256, 0, stream>>>(xpw, ws);
  k3b_scan    <<<dim3(2048,2), 256, 0, stream>>>(dtw, dtb, alog, Ds, ws);
  k3c_combine <<<dim3(128,2),  256, 0, stream>>>(ws);
  k0_transpose<<<dim3(64,2),   256, 0, stream>>>(f2w, ws);
  k4a_proj    <<<dim3(256,2),  256, 0, stream>>>(mag, ph, onw, onb, opw, ws);
  k4b_mlp     <<<dim3(512,2),  256, 0, stream>>>(n2w, n2b, f1w, f1b, f2b, ws);
  k5_final    <<<dim3(8192),   256, 0, stream>>>(ws, out);
}

// Round 7
// 835.406 us; speedup vs baseline: 3.3626x; 1.1139x over previous
//
#include <hip/hip_runtime.h>
#include <math.h>

// Problem constants
#define LL   4096      // H*W
#define DI   128       // 2*C
#define CC   64        // C
#define BB   8         // batch
#define KK   4         // scan directions
#define LB   32768     // pixels per instance
#define NPIX 2097152   // B*H*W*C elements of s
#define EPSF 1e-5f

// Workspace layout (floats, per instance)
#define OFF_XCIN   ((size_t)0)
#define OFF_XCONV  ((size_t)4194304)
#define OFF_XCONVT ((size_t)8388608)
#define OFF_Z      ((size_t)12582912)
#define OFF_Y      ((size_t)16777216)
#define OFF_YT     ((size_t)20971520)
#define OFF_XDBL   ((size_t)25165824)
#define ISTRIDE    ((size_t)25952256)   // floats per instance
// Aliases (lifetime-disjoint reuse):
#define OFF_YCOMBT OFF_XCIN             // xcin dead after k2; ycombT (d-major) by k3c
#define OFF_XNEW   OFF_YT               // yT dead after k3c; xnew (pixel-major) by k4a
#define OFF_SB     OFF_Y                // y dead after k3c; sbuf by k4b
#define OFF_F2WT   (OFF_Y + (size_t)2097152)  // f2w transposed (16384 floats)

__device__ __forceinline__ float sigmoidf_(float x){ return 1.f/(1.f+expf(-x)); }
__device__ __forceinline__ float softplusf_(float x){ return fmaxf(x,0.f) + log1pf(expf(-fabsf(x))); }
__device__ __forceinline__ float geluf_(float x){ return 0.5f*x*(1.f+erff(x*0.70710678118f)); }

#define LD16(dst, ptr) { const float4* p4_=(const float4*)(ptr);                 \
  float4 v0_=p4_[0], v1_=p4_[1], v2_=p4_[2], v3_=p4_[3];                         \
  dst[0]=v0_.x; dst[1]=v0_.y; dst[2]=v0_.z; dst[3]=v0_.w;                        \
  dst[4]=v1_.x; dst[5]=v1_.y; dst[6]=v1_.z; dst[7]=v1_.w;                        \
  dst[8]=v2_.x; dst[9]=v2_.y; dst[10]=v2_.z; dst[11]=v2_.w;                      \
  dst[12]=v3_.x; dst[13]=v3_.y; dst[14]=v3_.z; dst[15]=v3_.w; }
#define LD16R(dst, ptr) { const float4* p4_=(const float4*)(ptr);                \
  float4 v0_=p4_[0], v1_=p4_[1], v2_=p4_[2], v3_=p4_[3];                         \
  dst[15]=v0_.x; dst[14]=v0_.y; dst[13]=v0_.z; dst[12]=v0_.w;                    \
  dst[11]=v1_.x; dst[10]=v1_.y; dst[9]=v1_.z;  dst[8]=v1_.w;                     \
  dst[7]=v2_.x;  dst[6]=v2_.y;  dst[5]=v2_.z;  dst[4]=v2_.w;                     \
  dst[3]=v3_.x;  dst[2]=v3_.y;  dst[1]=v3_.z;  dst[0]=v3_.w; }

// K1: block = 4 waves over the SAME 64 pixels (lane = pixel). Wave ch handles a
// 64-row chunk of the 256 in_proj outputs (ch 0-1: xc, ch 2-3: z).
__global__ __launch_bounds__(256) void k1_ln_inproj(
    const float* __restrict__ xmag, const float* __restrict__ xph,
    const float* __restrict__ n1w_, const float* __restrict__ n1b_,
    const float* __restrict__ ipw_, float* __restrict__ ws)
{
  const int i = blockIdx.y;
  const float* xin = i ? xph : xmag;
  const float* n1w = n1w_ + i*CC;
  const float* n1b = n1b_ + i*CC;
  const float* ipw = ipw_ + i*2*DI*CC;
  float* base = ws + (size_t)i*ISTRIDE;
  const int t = threadIdx.x, lane = t & 63;
  const int ch = __builtin_amdgcn_readfirstlane(t >> 6);
  const int p = blockIdx.x*64 + lane;
  const int b = p >> 12, l = p & (LL-1);
  float hn[CC];
  LD16(hn, xin + (size_t)p*CC);
  LD16((hn+16), xin + (size_t)p*CC + 16);
  LD16((hn+32), xin + (size_t)p*CC + 32);
  LD16((hn+48), xin + (size_t)p*CC + 48);
  float s1=0.f, s2=0.f;
  #pragma unroll
  for(int c=0;c<CC;++c){ s1 += hn[c]; s2 += hn[c]*hn[c]; }
  const float mu = s1*(1.f/CC);
  const float rs = rsqrtf(s2*(1.f/CC) - mu*mu + EPSF);
  #pragma unroll
  for(int c=0;c<CC;++c) hn[c] = (hn[c]-mu)*rs*n1w[c] + n1b[c];
  if(ch < 2){
    float* xcb = base + OFF_XCIN + (size_t)b*DI*LL + l;
    #pragma unroll 2
    for(int jj=0;jj<64;++jj){
      const int j = ch*64 + jj;
      const float* wr = ipw + j*CC;
      float acc = 0.f;
      #pragma unroll
      for(int c=0;c<CC;++c) acc += hn[c]*wr[c];
      xcb[(size_t)j*LL] = acc;
    }
  } else {
    float* zT = base + OFF_Z;
    #pragma unroll 2
    for(int jj=0;jj<64;++jj){
      const int d = (ch-2)*64 + jj;
      const float* wr = ipw + (DI+d)*CC;
      float acc = 0.f;
      #pragma unroll
      for(int c=0;c<CC;++c) acc += hn[c]*wr[c];
      zT[(size_t)d*LB + p] = acc * sigmoidf_(acc);
    }
  }
}

// K2: depthwise 3x3 conv + silu; per (b,d) 64x64 tile via LDS; row-major + transposed out
__global__ __launch_bounds__(256) void k2_dwconv(
    const float* __restrict__ cw_, float* __restrict__ ws)
{
  const int i = blockIdx.y;
  const int bd = blockIdx.x;
  const int d = bd & (DI-1);
  const float* cw = cw_ + i*DI*9 + d*9;
  const float* xcin  = ws + (size_t)i*ISTRIDE + OFF_XCIN  + (size_t)bd*LL;
  float* xconv  = ws + (size_t)i*ISTRIDE + OFF_XCONV  + (size_t)bd*LL;
  float* xconvT = ws + (size_t)i*ISTRIDE + OFF_XCONVT + (size_t)bd*LL;
  __shared__ float tin[64*65];
  __shared__ float tout[64*65];
  const int t = threadIdx.x;
  float w9[9];
  #pragma unroll
  for(int q=0;q<9;++q) w9[q] = cw[q];
  for(int idx=t; idx<4096; idx+=256)
    tin[(idx>>6)*65 + (idx&63)] = xcin[idx];
  __syncthreads();
  const int w = t & 63, hb = (t>>6)*16;
  #pragma unroll
  for(int r=0;r<16;++r){
    const int h = hb + r;
    float acc = 0.f;
    #pragma unroll
    for(int dy=0;dy<3;++dy){
      const int hh = h + dy - 1;
      if(hh>=0 && hh<64){
        #pragma unroll
        for(int dx=0;dx<3;++dx){
          const int ww = w + dx - 1;
          if(ww>=0 && ww<64) acc += tin[hh*65+ww]*w9[dy*3+dx];
        }
      }
    }
    const float o = acc * sigmoidf_(acc);
    tout[h*65+w] = o;
    xconv[h*64+w] = o;
  }
  __syncthreads();
  const int hcol = t & 63, wb = (t>>6)*16;
  #pragma unroll
  for(int r=0;r<16;++r){
    const int wp = wb + r;
    xconvT[wp*64 + hcol] = tout[hcol*65 + wp];
  }
}

// K3a: x_dbl = x_proj(xs) -> (dts[4], Bs, Cs) per (b,k,scan-pos)
__global__ __launch_bounds__(256) void k3a_xproj(
    const float* __restrict__ xpw_, float* __restrict__ ws)
{
  const int i = blockIdx.z;
  const int b = blockIdx.y >> 2;
  const int k = blockIdx.y & 3;
  const int l = blockIdx.x*256 + threadIdx.x;
  const float* src = ws + (size_t)i*ISTRIDE + ((k&1)? OFF_XCONVT : OFF_XCONV) + (size_t)b*DI*LL;
  const int ridx = (k>=2) ? (LL-1-l) : l;
  const float* xpw = xpw_ + i*KK*6*DI + k*6*DI;
  float acc[6] = {0,0,0,0,0,0};
  for(int d=0; d<DI; ++d){
    const float xv = src[(size_t)d*LL + ridx];
    #pragma unroll
    for(int c=0;c<6;++c) acc[c] += xv * xpw[c*DI + d];
  }
  float* xdbl = ws + (size_t)i*ISTRIDE + OFF_XDBL + (size_t)(b*KK+k)*6*LL;
  #pragma unroll
  for(int c=0;c<6;++c) xdbl[(size_t)c*LL + l] = acc[c];
}

// K3b v3: paired fwd/bwd selective scan. Phase-split for low register pressure;
// wave shuffle scan + single barrier for the cross-wave aggregate exchange.
__global__ __launch_bounds__(256,3) void k3b_scan(
    const float* __restrict__ dtw_, const float* __restrict__ dtb_,
    const float* __restrict__ alog_, const float* __restrict__ Ds_,
    float* __restrict__ ws)
{
  const int gid = blockIdx.x;           // b*256 + kp*128 + d
  const int i = blockIdx.y;
  const int d  = gid & (DI-1);
  const int kp = (gid >> 7) & 1;
  const int b  = gid >> 8;
  const int t = threadIdx.x, lane = t & 63, wv = t >> 6;
  float* base = ws + (size_t)i*ISTRIDE;
  const float* src = base + (kp? OFF_XCONVT : OFF_XCONV) + (size_t)(b*DI+d)*LL;
  float*       dst = base + (kp? OFF_YT    : OFF_Y    ) + (size_t)(b*DI+d)*LL;
  const float* xdF = base + OFF_XDBL + (size_t)(b*KK+kp  )*6*LL;
  const float* xdB = base + OFF_XDBL + (size_t)(b*KK+kp+2)*6*LL;
  const int kdF = kp*DI + d, kdB = (kp+2)*DI + d;
  const float4 wF = ((const float4*)dtw_)[i*KK*DI + kdF];
  const float4 wB = ((const float4*)dtw_)[i*KK*DI + kdB];
  const float biasF = dtb_[i*KK*DI + kdF], biasB = dtb_[i*KK*DI + kdB];
  const float AvF = -expf(alog_[i*KK*DI + kdF]);
  const float AvB = -expf(alog_[i*KK*DI + kdB]);
  const float Dsum = Ds_[i*KK*DI + kdF] + Ds_[i*KK*DI + kdB];
  const int l0 = t*16;
  const int s0 = LL - 16 - l0;

  float vX[16], aF[16], bF[16], aB[16], bB[16];
  float fA = 1.f, fB = 0.f, gA = 1.f, gB = 0.f;
  LD16(vX, src + l0);

  { // ---- forward phase: build aF,bF + thread aggregate ----
    float pre[16], r0[16];
    LD16(r0, xdF + 0*LL + l0);
    #pragma unroll
    for(int j=0;j<16;++j) pre[j] = biasF + wF.x*r0[j];
    LD16(r0, xdF + 1*LL + l0);
    #pragma unroll
    for(int j=0;j<16;++j) pre[j] += wF.y*r0[j];
    LD16(r0, xdF + 2*LL + l0);
    #pragma unroll
    for(int j=0;j<16;++j) pre[j] += wF.z*r0[j];
    LD16(r0, xdF + 3*LL + l0);
    #pragma unroll
    for(int j=0;j<16;++j) pre[j] += wF.w*r0[j];
    LD16(r0, xdF + 4*LL + l0);   // Bs
    #pragma unroll
    for(int j=0;j<16;++j){
      const float delta = softplusf_(pre[j]);
      aF[j] = expf(delta*AvF);
      bF[j] = delta*r0[j]*vX[j];
      fB = fB*aF[j] + bF[j];
      fA *= aF[j];
    }
  }
  { // ---- backward phase: build aB,bB + thread aggregate (suffix) ----
    float pre[16], r0[16];
    LD16R(r0, xdB + 0*LL + s0);
    #pragma unroll
    for(int j=0;j<16;++j) pre[j] = biasB + wB.x*r0[j];
    LD16R(r0, xdB + 1*LL + s0);
    #pragma unroll
    for(int j=0;j<16;++j) pre[j] += wB.y*r0[j];
    LD16R(r0, xdB + 2*LL + s0);
    #pragma unroll
    for(int j=0;j<16;++j) pre[j] += wB.z*r0[j];
    LD16R(r0, xdB + 3*LL + s0);
    #pragma unroll
    for(int j=0;j<16;++j) pre[j] += wB.w*r0[j];
    LD16R(r0, xdB + 4*LL + s0);  // Bs reversed
    #pragma unroll
    for(int j=15;j>=0;--j){
      const float delta = softplusf_(pre[j]);
      aB[j] = expf(delta*AvB);
      bB[j] = delta*r0[j]*vX[j];
      gB = gB*aB[j] + bB[j];
      gA *= aB[j];
    }
  }

  // ---- wave shuffle scans ----
  #pragma unroll
  for(int off=1; off<64; off<<=1){
    const float aL = __shfl_up(fA, off);
    const float bL = __shfl_up(fB, off);
    if(lane >= off){ fB = bL*fA + fB; fA = aL*fA; }
  }
  float pA = __shfl_up(fA, 1), pB = __shfl_up(fB, 1);
  if(lane==0){ pA=1.f; pB=0.f; }
  #pragma unroll
  for(int off=1; off<64; off<<=1){
    const float aR = __shfl_down(gA, off);
    const float bR = __shfl_down(gB, off);
    if(lane + off < 64){ gB = gA*bR + gB; gA = gA*aR; }
  }
  float qA = __shfl_down(gA, 1), qB = __shfl_down(gB, 1);
  if(lane==63){ qA=1.f; qB=0.f; }

  // ---- cross-wave aggregate exchange (1 barrier) ----
  __shared__ float wAg[4], wBg[4], vAg[4], vBg[4];
  if(lane==63){ wAg[wv]=fA; wBg[wv]=fB; }
  if(lane==0){ vAg[wv]=gA; vBg[wv]=gB; }
  __syncthreads();
  float eA=1.f, eB=0.f;               // prefix over waves < wv
  for(int u=0; u<wv; ++u){ eB = wAg[u]*eB + wBg[u]; eA *= wAg[u]; }
  float rA=1.f, rB=0.f;               // suffix over waves > wv
  for(int u=3; u>wv; --u){ rB = vAg[u]*rB + vBg[u]; rA *= vAg[u]; }

  float hf = pA*eB + pB;              // state entering chunk from the left
  float hb = qA*rB + qB;              // state entering chunk from the right

  // ---- output ----
  float out[16], cc[16];
  LD16(cc, xdF + 5*LL + l0);          // Cs fwd
  #pragma unroll
  for(int j=0;j<16;++j){
    hf = aF[j]*hf + bF[j];
    out[j] = hf*cc[j] + Dsum*vX[j];
  }
  LD16R(cc, xdB + 5*LL + s0);         // Cs bwd (reversed)
  #pragma unroll
  for(int j=15;j>=0;--j){
    hb = aB[j]*hb + bB[j];
    out[j] += hb*cc[j];
  }
  float4* d4 = (float4*)(dst + l0);
  d4[0] = make_float4(out[0],out[1],out[2],out[3]);
  d4[1] = make_float4(out[4],out[5],out[6],out[7]);
  d4[2] = make_float4(out[8],out[9],out[10],out[11]);
  d4[3] = make_float4(out[12],out[13],out[14],out[15]);
}

// K3c: combine y + transpose(yT) into d-major ycombT[d][b*LL+l].
__global__ __launch_bounds__(256) void k3c_combine(float* __restrict__ ws)
{
  const int i = blockIdx.y;
  const int b = blockIdx.x >> 4;
  const int tile = blockIdx.x & 15;
  const int h0 = (tile >> 2) * 16, w0 = (tile & 3) * 16;
  const int t = threadIdx.x;
  float* base = ws + (size_t)i*ISTRIDE;
  const float* y  = base + OFF_Y;
  const float* yT = base + OFF_YT;
  float* ycT = base + OFF_YCOMBT;
  __shared__ float ytile[16*16*16];
  __shared__ float ytT[16*16*17];
  const int r0 = t >> 4, c0 = t & 15;
  const int hi = t >> 4, wi = t & 15;
  const int l = (h0 + hi)*64 + (w0 + wi);
  for(int dc=0; dc<8; ++dc){
    #pragma unroll 4
    for(int dd=0; dd<16; ++dd){
      const int d = dc*16 + dd;
      const size_t rb = (size_t)(b*DI + d)*LL;
      ytile[dd*256 + t] = y[rb + (size_t)(h0 + r0)*64 + (w0 + c0)];
      ytT[dd*272 + r0*17 + c0] = yT[rb + (size_t)(w0 + r0)*64 + (h0 + c0)];
    }
    __syncthreads();
    #pragma unroll 4
    for(int dd=0; dd<16; ++dd){
      const int d = dc*16 + dd;
      ycT[(size_t)d*LB + b*LL + l] = ytile[dd*256 + t] + ytT[dd*272 + wi*17 + hi];
    }
    __syncthreads();
  }
}

// K0t: transpose f2w (64x256) -> f2wT (256x64)
__global__ __launch_bounds__(256) void k0_transpose(
    const float* __restrict__ f2w_, float* __restrict__ ws)
{
  const int i = blockIdx.y;
  const int idx = blockIdx.x*256 + threadIdx.x;
  const float v = f2w_[i*16384 + idx];
  const int o = idx >> 8, j = idx & 255;
  ws[(size_t)i*ISTRIDE + OFF_F2WT + (size_t)j*64 + o] = v;
}

// K4a: block = 4 waves = 2 pixel-groups x 2 K-chunks. lane = pixel.
__global__ __launch_bounds__(256) void k4a_proj(
    const float* __restrict__ xmag, const float* __restrict__ xph,
    const float* __restrict__ onw_, const float* __restrict__ onb_,
    const float* __restrict__ opw_, float* __restrict__ ws)
{
  const int i = blockIdx.y;
  const float* xin = i ? xph : xmag;
  const float* onw = onw_ + i*DI;
  const float* onb = onb_ + i*DI;
  const float* opw = opw_ + i*CC*DI;
  float* base = ws + (size_t)i*ISTRIDE;
  const float* ycT = base + OFF_YCOMBT;
  const float* zT  = base + OFF_Z;
  const int t = threadIdx.x, lane = t & 63, wv = t >> 6;
  const int g = wv >> 1;
  const int ch = __builtin_amdgcn_readfirstlane(wv & 1);
  const int p = blockIdx.x*128 + g*64 + lane;
  float yv[64];
  float s1=0.f, s2=0.f;
  #pragma unroll 8
  for(int c=0;c<64;++c){
    const float v = ycT[(size_t)(ch*64+c)*LB + p];
    yv[c]=v; s1+=v; s2+=v*v;
  }
  __shared__ float st[2][64][4];
  st[g][lane][ch*2]=s1; st[g][lane][ch*2+1]=s2;
  __syncthreads();
  const float S1 = st[g][lane][0]+st[g][lane][2];
  const float S2 = st[g][lane][1]+st[g][lane][3];
  const float mu = S1*(1.f/DI);
  const float rs = rsqrtf(S2*(1.f/DI) - mu*mu + EPSF);
  #pragma unroll 8
  for(int c=0;c<64;++c){
    const int d = ch*64+c;
    yv[c] = ((yv[c]-mu)*rs*onw[d] + onb[d]) * zT[(size_t)d*LB + p];
  }
  float acc[64];
  #pragma unroll 2
  for(int o=0;o<64;++o){
    const float* wr = opw + o*DI + ch*64;
    float a = 0.f;
    #pragma unroll
    for(int c=0;c<64;++c) a += yv[c]*wr[c];
    acc[o] = a;
  }
  __shared__ float ab[2][64*65];
  if(ch==0){
    #pragma unroll 8
    for(int o=0;o<64;++o) ab[g][lane*65+o] = acc[o];
  }
  __syncthreads();
  if(ch==1){
    #pragma unroll 8
    for(int o=0;o<64;++o) ab[g][lane*65+o] += acc[o];
  }
  __syncthreads();
  const int pxl = t >> 1, oh = (t & 1)*32;
  const int gg = pxl >> 6, ll = pxl & 63;
  const int pg = blockIdx.x*128 + pxl;
  float* xnew = base + OFF_XNEW + (size_t)pg*CC + oh;
  const float* xi = xin + (size_t)pg*CC + oh;
  #pragma unroll
  for(int q=0;q<8;++q){
    float4 v;
    v.x = ab[gg][ll*65+oh+4*q  ] + xi[4*q  ];
    v.y = ab[gg][ll*65+oh+4*q+1] + xi[4*q+1];
    v.z = ab[gg][ll*65+oh+4*q+2] + xi[4*q+2];
    v.w = ab[gg][ll*65+oh+4*q+3] + xi[4*q+3];
    ((float4*)xnew)[q] = v;
  }
}

// K4b v3: block = 4 waves over the SAME 64 pixels (lane = pixel). Wave w owns
// output chunk [16w,16w+16). Per round r, wave w computes 16 fc1+GELU hidden
// values (j = 64r+16w+m), stages them in LDS g[64][64], then every wave
// consumes all 64 staged j's for its 16 outputs. acc[16] stays in VGPRs.
__global__ __launch_bounds__(256,3) void k4b_mlp(
    const float* __restrict__ n2w_, const float* __restrict__ n2b_,
    const float* __restrict__ f1w_, const float* __restrict__ f1b_,
    const float* __restrict__ f2b_, float* __restrict__ ws)
{
  const int i = blockIdx.y;
  const float* n2w = n2w_ + i*CC;
  const float* n2b = n2b_ + i*CC;
  const float* f1w = f1w_ + i*4*CC*CC;
  const float* f1b = f1b_ + i*4*CC;
  const float* f2b = f2b_ + i*CC;
  float* base = ws + (size_t)i*ISTRIDE;
  const float* f2wT = base + OFF_F2WT;
  const float* xnew = base + OFF_XNEW;
  const int t = threadIdx.x, lane = t & 63;
  const int wv = __builtin_amdgcn_readfirstlane(t >> 6);
  const int p = blockIdx.x*64 + lane;
  float h2[64];
  LD16(h2, xnew + (size_t)p*CC);
  LD16((h2+16), xnew + (size_t)p*CC + 16);
  LD16((h2+32), xnew + (size_t)p*CC + 32);
  LD16((h2+48), xnew + (size_t)p*CC + 48);
  float s1=0.f, s2=0.f;
  #pragma unroll
  for(int c=0;c<CC;++c){ s1 += h2[c]; s2 += h2[c]*h2[c]; }
  const float mu = s1*(1.f/CC);
  const float rs = rsqrtf(s2*(1.f/CC) - mu*mu + EPSF);
  #pragma unroll
  for(int c=0;c<CC;++c) h2[c] = (h2[c]-mu)*rs*n2w[c] + n2b[c];
  float acc[16];
  #pragma unroll
  for(int o=0;o<16;++o) acc[o] = 0.f;
  __shared__ float g[64*64];
  for(int r=0;r<4;++r){
    float gv[16];
    const int jb = r*64 + wv*16;
    #pragma unroll 2
    for(int m=0;m<16;++m){
      const float* w1r = f1w + (jb+m)*CC;
      float gvv = f1b[jb+m];
      #pragma unroll
      for(int c=0;c<CC;++c) gvv += h2[c]*w1r[c];
      gv[m] = geluf_(gvv);
    }
    __syncthreads();   // prior round's reads of g complete
    #pragma unroll
    for(int m=0;m<16;++m) g[(wv*16+m)*64 + lane] = gv[m];
    __syncthreads();
    #pragma unroll 4
    for(int jj=0;jj<64;++jj){
      const float gvv = g[jj*64 + lane];
      const float* w2r = f2wT + (size_t)(r*64+jj)*64 + wv*16;
      #pragma unroll
      for(int o=0;o<16;++o) acc[o] += gvv*w2r[o];
    }
  }
  // store: lane writes its 16-output chunk = one full 64B line
  const float* xr = xnew + (size_t)p*CC + wv*16;
  float* sb = base + OFF_SB + (size_t)p*CC + wv*16;
  #pragma unroll
  for(int q=0;q<4;++q){
    const float4 x4 = ((const float4*)xr)[q];
    float4 v;
    v.x = acc[4*q  ] + f2b[wv*16+4*q  ] + x4.x;
    v.y = acc[4*q+1] + f2b[wv*16+4*q+1] + x4.y;
    v.z = acc[4*q+2] + f2b[wv*16+4*q+2] + x4.z;
    v.w = acc[4*q+3] + f2b[wv*16+4*q+3] + x4.w;
    ((float4*)sb)[q] = v;
  }
}

// K5: s = inst0 + inst1; write to both output halves
__global__ __launch_bounds__(256) void k5_final(
    const float* __restrict__ ws, float* __restrict__ out)
{
  const int idx = blockIdx.x*256 + threadIdx.x;
  const float v = ws[OFF_SB + idx] + ws[ISTRIDE + OFF_SB + idx];
  out[idx] = v;
  out[NPIX + idx] = v;
}

extern "C" void kernel_launch(void* const* d_in, const int* in_sizes, int n_in,
                              void* d_out, int out_size, void* d_ws, size_t ws_size,
                              hipStream_t stream)
{
  const float* mag  = (const float*)d_in[0];
  const float* ph   = (const float*)d_in[1];
  const float* n1w  = (const float*)d_in[2];
  const float* n1b  = (const float*)d_in[3];
  const float* ipw  = (const float*)d_in[4];
  const float* cw   = (const float*)d_in[5];
  const float* xpw  = (const float*)d_in[6];
  const float* dtw  = (const float*)d_in[7];
  const float* dtb  = (const float*)d_in[8];
  const float* alog = (const float*)d_in[9];
  const float* Ds   = (const float*)d_in[10];
  const float* onw  = (const float*)d_in[11];
  const float* onb  = (const float*)d_in[12];
  const float* opw  = (const float*)d_in[13];
  const float* n2w  = (const float*)d_in[14];
  const float* n2b  = (const float*)d_in[15];
  const float* f1w  = (const float*)d_in[16];
  const float* f1b  = (const float*)d_in[17];
  const float* f2w  = (const float*)d_in[18];
  const float* f2b  = (const float*)d_in[19];
  float* ws = (float*)d_ws;
  float* out = (float*)d_out;

  k1_ln_inproj<<<dim3(512,2),  256, 0, stream>>>(mag, ph, n1w, n1b, ipw, ws);
  k2_dwconv   <<<dim3(1024,2), 256, 0, stream>>>(cw, ws);
  k3a_xproj   <<<dim3(16,32,2),256, 0, stream>>>(xpw, ws);
  k3b_scan    <<<dim3(2048,2), 256, 0, stream>>>(dtw, dtb, alog, Ds, ws);
  k3c_combine <<<dim3(128,2),  256, 0, stream>>>(ws);
  k0_transpose<<<dim3(64,2),   256, 0, stream>>>(f2w, ws);
  k4a_proj    <<<dim3(256,2),  256, 0, stream>>>(mag, ph, onw, onb, opw, ws);
  k4b_mlp     <<<dim3(512,2),  256, 0, stream>>>(n2w, n2b, f1w, f1b, f2b, ws);
  k5_final    <<<dim3(8192),   256, 0, stream>>>(ws, out);
}